// Round 15
// baseline (145.155 us; speedup 1.0000x reference)
//
#include <hip/hip_runtime.h>
#include <hip/hip_bf16.h>
#include <math.h>

// Self_Attention_Local R20: work-preserving occupancy doubling.
//   R19's i-split inflated QKV work 4x (half-empty A operands, 4x blocks).
//   R20 keeps R16's block = (patch-group of 4, head), SAME total work and
//   SAME 40KB LDS zones, but 512 threads = 8 waves: wave w8 = (patch
//   plw=w8>>1, i-half ih=w8&1). Per block: QKV 24 full tiles (3/wave),
//   scores 256 MFMA, PV 128, out-GEMM 32 -- all unchanged vs R16; only
//   stats duplicate (x2, 12 MFMAs). 1024 blocks x 8 waves = 8192 waves,
//   LDS 40KB -> 4 blocks/CU -> 32 waves/CU (2x R16), half work per wave.
//   P slabs: wave's 4 chunks (512 shorts) fill its own pair of dead zones
//   ({QT,QN}[plw] ih=0, {KN,VS}[plw] ih=1); KT[plw] live for amk; CTX
//   overlays KT[plw] behind new barriers (zones now shared by sibling
//   waves -> 4 barriers total). All formulas verbatim R16 with w->plw,
//   i-tile nt -> ih*4+nt.
//   KEPT: XCD swizzle, setprio, R13 rotated out-GEMM, f2bf, 6-shuffle
//   butterfly, R8 LDS keys.
//   DEAD: v_cvt_pk_bf16_f32 (R17), i-split-by-block (R19 work inflation).
//   QUARANTINED: gh-shortcut, cross-loop lookahead (R12 spill).

typedef short bfrag __attribute__((ext_vector_type(8)));   // 8 bf16 = 4 VGPRs
typedef float f32x4 __attribute__((ext_vector_type(4)));

static __device__ __forceinline__ short f2bf(float x) {
    __hip_bfloat16 h = __float2bfloat16(x);
    return __builtin_bit_cast(short, h);
}
static __device__ __forceinline__ bfrag bzero() {
    bfrag z;
    #pragma unroll
    for (int j = 0; j < 8; ++j) z[j] = 0;
    return z;
}

// ---------------- convertW: 128 blocks ----------------
__global__ __launch_bounds__(256) void convertW(
    const float* __restrict__ Wq, const float* __restrict__ Wk,
    const float* __restrict__ Wv, const float* __restrict__ Wout,
    short* __restrict__ Wp, short* __restrict__ Wout_pt,
    float* __restrict__ out)
{
    __shared__ short lt[128 * 33];          // union: [32][129] or [128][33]
    const int b = blockIdx.x, t = threadIdx.x;

    // zero out: 524288 floats = 131072 float4 = 128 blocks x 1024
    {
        float4* o4 = (float4*)out;
        const int zb = b * 1024 + t;
        #pragma unroll
        for (int k = 0; k < 4; ++k)
            o4[zb + k * 256] = make_float4(0.f, 0.f, 0.f, 0.f);
    }

    if (b < 96) {
        const int x = b >> 5, h = (b >> 2) & 7, k0 = (b & 3) * 32;
        const float* W = (x == 0) ? Wq : (x == 1) ? Wk : Wv;
        #pragma unroll 4
        for (int rr = 0; rr < 16; ++rr) {
            const int k = rr * 2 + (t >> 7);          // 0..31
            const int i = t & 127;
            lt[k * 129 + i] = f2bf(W[(k0 + k) * 1024 + i * 8 + h]);
        }
        __syncthreads();
        short* dst = Wp + (x * 8 + h) * 16384;
        #pragma unroll
        for (int pp = 0; pp < 4; ++pp) {
            const int i  = pp * 32 + (t >> 3);
            const int kk = (t & 7) * 4;
            short4 v;
            v.x = lt[(kk + 0) * 129 + i]; v.y = lt[(kk + 1) * 129 + i];
            v.z = lt[(kk + 2) * 129 + i]; v.w = lt[(kk + 3) * 129 + i];
            *(short4*)&dst[i * 128 + k0 + kk] = v;
        }
    } else {
        const int b2 = b - 96, h = b2 >> 2, c0 = (b2 & 3) * 32;
        #pragma unroll 4
        for (int rr = 0; rr < 16; ++rr) {
            const int i = rr * 8 + (t >> 5);
            const int c = t & 31;
            lt[i * 33 + c] = f2bf(Wout[(i * 8 + h) * 128 + c0 + c]);
        }
        __syncthreads();
        short* dst = Wout_pt + h * 16384;
        #pragma unroll
        for (int pp = 0; pp < 4; ++pp) {
            const int c  = pp * 8 + (t >> 5);
            const int i0 = (t & 31) * 4;
            short4 v;
            v.x = lt[(i0 + 0) * 33 + c]; v.y = lt[(i0 + 1) * 33 + c];
            v.z = lt[(i0 + 2) * 33 + c]; v.w = lt[(i0 + 3) * 33 + c];
            *(short4*)&dst[(c0 + c) * 128 + i0] = v;
        }
    }
}

// ---------------- attn4 ----------------
// Block = (patch-group of 4, head), 512 threads = 8 waves.
// Wave w8: patch plw = w8>>1, i-half ih = w8&1.
// LDS zones (shorts), 40 KB (R16 layout, per-patch subregions +plw*1024):
//   QT [0..4095]      Qt[pl][i][p]    (dies -> ih=0 P chunks 0,1)
//   KT [4096..8191]   Kt[pl][j][p]    (live in band loop; CTX after bar3)
//   QN [8192..12287]  Q natural, swz  (dies -> ih=0 P chunks 2,3)
//   KN [12288..16383] K natural, swz  (dies -> ih=1 P chunks 0,1)
//   VS [16384..20479] V natural, swz  (dies -> ih=1 P chunks 2,3)
#define QT   0
#define KT   4096
#define QN   8192
#define KN   12288
#define VS   16384
#define CTXK 4096

__global__ __launch_bounds__(512, 8) void attn4(
    const float* __restrict__ emb,      // [4096][128] fp32
    const short* __restrict__ Wp,       // [3][8][128 i][128 k]
    const short* __restrict__ Wout_pt,  // [8][128 col][128 i]
    float* __restrict__ out)            // [4096][128] fp32, atomic target
{
    __shared__ short lds[20480];        // 40 KB -> 4 blocks/CU
    const int bid = blockIdx.x;         // 0..1023
    // XCD-aware swizzle: heads of one patch-group share bid mod 8 -> same XCD
    const int pg  = bid & 127;          // patch group of 4
    const int h   = bid >> 7;           // head
    const int t   = threadIdx.x;        // 0..511
    const int w8   = t >> 6;            // wave 0..7
    const int plw  = w8 >> 1;           // patch 0..3
    const int ih   = w8 & 1;            // i-half
    const int lane = t & 63;
    const int m16  = lane & 15;
    const int quad = lane >> 4;
    const int q8   = quad * 8;

    // ================= QKV: (32x128) @ W_h (128x128) x3 =================
    // 24 i-tiles split 3 per wave; stores verbatim R16.
    {
        bfrag a[2][4];
        #pragma unroll
        for (int tm = 0; tm < 2; ++tm)
            #pragma unroll
            for (int ks = 0; ks < 4; ++ks) {
                const float* er = emb + (size_t)(pg*32 + tm*16 + m16) * 128 + ks*32 + q8;
                const float4 x0 = *(const float4*)er;
                const float4 x1 = *(const float4*)(er + 4);
                bfrag f;
                f[0]=f2bf(x0.x); f[1]=f2bf(x0.y); f[2]=f2bf(x0.z); f[3]=f2bf(x0.w);
                f[4]=f2bf(x1.x); f[5]=f2bf(x1.y); f[6]=f2bf(x1.z); f[7]=f2bf(x1.w);
                a[tm][ks] = f;
            }

        #pragma unroll
        for (int tt = 0; tt < 3; ++tt) {
            const int nt = w8 * 3 + tt;           // 0..23 = {q,k,v} x 8 i-tiles
            const int x  = nt >> 3;
            const int i0 = (nt & 7) * 16;
            const short* Wb = Wp + ((x*8 + h)*128 + i0 + m16) * 128;
            bfrag bb[4];
            #pragma unroll
            for (int ks = 0; ks < 4; ++ks)
                bb[ks] = *(const bfrag*)&Wb[ks*32 + q8];
            f32x4 c0 = {0.f,0.f,0.f,0.f}, c1 = {0.f,0.f,0.f,0.f};
            __builtin_amdgcn_s_setprio(1);
            #pragma unroll
            for (int ks = 0; ks < 4; ++ks) {
                c0 = __builtin_amdgcn_mfma_f32_16x16x32_bf16(a[0][ks], bb[ks], c0, 0,0,0);
                c1 = __builtin_amdgcn_mfma_f32_16x16x32_bf16(a[1][ks], bb[ks], c1, 0,0,0);
            }
            __builtin_amdgcn_s_setprio(0);
            #pragma unroll
            for (int tm = 0; tm < 2; ++tm) {
                const f32x4 cc = tm ? c1 : c0;
                const int mrow0 = tm*16 + quad*4;     // 4 consecutive tokens
                const int pl = mrow0 >> 3;            // local patch
                const int p0 = mrow0 & 7;             // 0 or 4
                const int col = i0 + m16;
                const int cb  = nt & 7;               // column block = i>>4
                if (x == 0) {
                    short4 v;
                    v.x = f2bf(cc[0]); v.y = f2bf(cc[1]);
                    v.z = f2bf(cc[2]); v.w = f2bf(cc[3]);
                    *(short4*)&lds[QT + pl*1024 + col*8 + p0] = v;   // Qt[i][p]
                    #pragma unroll
                    for (int r = 0; r < 4; ++r)       // Qn[p][i], block-swz
                        lds[QN + pl*1024 + (p0 + r)*128
                            + ((cb ^ ((p0 + r) & 3)) << 4) + m16] = f2bf(cc[r]);
                } else if (x == 1) {
                    short4 v;
                    v.x = f2bf(cc[0]); v.y = f2bf(cc[1]);
                    v.z = f2bf(cc[2]); v.w = f2bf(cc[3]);
                    *(short4*)&lds[KT + pl*1024 + col*8 + p0] = v;   // Kt[j][p]
                    #pragma unroll
                    for (int r = 0; r < 4; ++r)       // Kn[p][j], block-swz
                        lds[KN + pl*1024 + (p0 + r)*128
                            + ((cb ^ ((p0 + r) & 3)) << 4) + m16] = f2bf(cc[r]);
                } else {
                    // Vs[p][j], column-group swizzled -> conflict-free
                    const int g = ((cb ^ (((pl & 1) << 1) | (p0 >> 2))) << 4);
                    #pragma unroll
                    for (int r = 0; r < 4; ++r)
                        lds[VS + pl*1024 + (p0 + r)*128 + g + m16] = f2bf(cc[r]);
                }
            }
        }
    }
    __syncthreads();   // barrier 1: cross-wave QKV exchange

    // ===== stats via Grams (redundant per i-half pair; reads patch plw) ====
    float rs2, nbias;
    {
        bfrag gq[4], gk[4], gs[4], ones;
        #pragma unroll
        for (int j = 0; j < 8; ++j) ones[j] = (short)0x3F80;   // bf16 1.0
        #pragma unroll
        for (int ks = 0; ks < 4; ++ks) {
            const int bswz = (((2*ks + (quad >> 1)) ^ (m16 & 3)) << 4) + (quad & 1)*8;
            gq[ks] = (m16 < 8) ? *(const bfrag*)&lds[QN + plw*1024 + m16*128 + bswz] : bzero();
            gk[ks] = (m16 < 8) ? *(const bfrag*)&lds[KN + plw*1024 + m16*128 + bswz] : bzero();
            gs[ks] = (m16 < 8) ? *(const bfrag*)&lds[QN + plw*1024 + m16*128 + bswz]
                               : *(const bfrag*)&lds[KN + plw*1024 + (m16 - 8)*128 + bswz];
        }
        f32x4 cg = {0.f,0.f,0.f,0.f}, ch = {0.f,0.f,0.f,0.f}, cs = {0.f,0.f,0.f,0.f};
        __builtin_amdgcn_s_setprio(1);
        #pragma unroll
        for (int ks = 0; ks < 4; ++ks) {
            cg = __builtin_amdgcn_mfma_f32_16x16x32_bf16(gq[ks], gq[ks], cg, 0,0,0);
            ch = __builtin_amdgcn_mfma_f32_16x16x32_bf16(gk[ks], gk[ks], ch, 0,0,0);
            cs = __builtin_amdgcn_mfma_f32_16x16x32_bf16(gs[ks], ones,  cs, 0,0,0);
        }
        __builtin_amdgcn_s_setprio(0);
        float gh = 0.f, sp = 0.f;
        #pragma unroll
        for (int r = 0; r < 4; ++r) {
            gh = fmaf(cg[r], ch[r], gh);
            sp = fmaf(cs[r], __shfl_xor(cs[r], 32), sp);     // sQ[p]*sK[p]
        }
        sp += __shfl_xor(sp, 16);
        #pragma unroll
        for (int off = 1; off <= 32; off <<= 1)
            gh += __shfl_xor(gh, off);
        const float mean = sp * (1.f / 16384.f);
        const float var  = gh * (1.f / 16384.f) - mean * mean;
        rs2   = rsqrtf(var + 1e-5f) * 1.44269504f;           // fold log2(e)
        nbias = -mean * rs2;
    }

    // ===== hoist Qt B-frags (own i-half) and V A-frags (patch plw) ========
    bfrag bs[4], av[4];
    #pragma unroll
    for (int nt = 0; nt < 4; ++nt)
        bs[nt] = (quad == 0)
            ? *(const bfrag*)&lds[QT + plw*1024 + (ih*64 + nt*16 + m16)*8] : bzero();
    #pragma unroll
    for (int ks = 0; ks < 4; ++ks) {
        if (m16 < 8) {
            const int g = (((2*ks + (quad >> 1)) ^ (((plw & 1) << 1) | (m16 >> 2))) << 4);
            av[ks] = *(const bfrag*)&lds[VS + plw*1024 + m16*128 + g + (quad & 1)*8];
        } else if (m16 == 8) {                 // ones ROW -> C[8][i] = rowsum_i
            bfrag o;
            #pragma unroll
            for (int j = 0; j < 8; ++j) o[j] = (short)0x3F80;
            av[ks] = o;
        } else
            av[ks] = bzero();
    }
    __syncthreads();   // barrier 2: zones read by sibling waves -> P overlay ok

    // ===== band loop: 8 bands, 4 i-tiles per wave; P in own dead zones =====
    // P chunk (ih, nt): ih=0 -> {QT,QN}[plw], ih=1 -> {KN,VS}[plw];
    // [16 i][32 j] = 512 shorts; formulas verbatim R16.
    const int key2 = m16 >> 2;
    const int rowoff = m16 * 32;
    f32x4 cc[4];
    #pragma unroll
    for (int nt = 0; nt < 4; ++nt) cc[nt] = (f32x4){0.f,0.f,0.f,0.f};

    #pragma unroll
    for (int ks = 0; ks < 4; ++ks) {
        #pragma unroll
        for (int jb = 0; jb < 2; ++jb) {
            const int band = ks*2 + jb;
            const bfrag amk = (quad == 0)
                ? *(const bfrag*)&lds[KT + plw*1024 + (band*16 + m16)*8] : bzero();
            const int tw = (((jb*2 + (quad >> 1)) ^ key2) << 3) + (quad & 1)*4;
            #pragma unroll
            for (int nt = 0; nt < 4; ++nt) {
                const int zb = (ih == 0) ? ((nt >> 1) ? QN : QT)
                                         : ((nt >> 1) ? VS : KN);
                f32x4 z = {0.f,0.f,0.f,0.f};
                __builtin_amdgcn_s_setprio(1);
                const f32x4 s4 = __builtin_amdgcn_mfma_f32_16x16x32_bf16(amk, bs[nt], z, 0,0,0);
                __builtin_amdgcn_s_setprio(0);
                short4 v;
                v.x = f2bf(__builtin_amdgcn_exp2f(fmaf(s4[0], rs2, nbias)));
                v.y = f2bf(__builtin_amdgcn_exp2f(fmaf(s4[1], rs2, nbias)));
                v.z = f2bf(__builtin_amdgcn_exp2f(fmaf(s4[2], rs2, nbias)));
                v.w = f2bf(__builtin_amdgcn_exp2f(fmaf(s4[3], rs2, nbias)));
                *(short4*)&lds[zb + plw*1024 + (nt & 1)*512 + rowoff + tw] = v;
            }
        }
        __builtin_amdgcn_s_setprio(1);
        #pragma unroll
        for (int nt = 0; nt < 4; ++nt) {
            const int zb = (ih == 0) ? ((nt >> 1) ? QN : QT)
                                     : ((nt >> 1) ? VS : KN);
            const bfrag bp = *(const bfrag*)
                &lds[zb + plw*1024 + (nt & 1)*512 + rowoff + ((quad ^ key2) << 3)];
            cc[nt] = __builtin_amdgcn_mfma_f32_16x16x32_bf16(av[ks], bp, cc[nt], 0,0,0);
        }
        __builtin_amdgcn_s_setprio(0);
    }

    __syncthreads();   // barrier 3: both waves of plw done with KT -> CTX overlay

    // ===== normalize once; ctx[p][i] -> KT[plw] (global i-tile ih*4+nt) ====
    #pragma unroll
    for (int nt = 0; nt < 4; ++nt) {
        const float s  = __shfl(cc[nt][0], 32 + m16);   // C[8][i] from quad-2
        const float is = 1.0f / s;
        if (quad < 2) {
            #pragma unroll
            for (int r = 0; r < 4; ++r) {
                const int p = quad*4 + r;
                lds[CTXK + plw*1024 + p*128 + (((ih*4 + nt) ^ (p & 3)) << 4) + m16] =
                    f2bf(cc[nt][r] * is);
            }
        }
    }
    __syncthreads();   // barrier 4: full CTX visible to both waves of plw

    // ===== out-GEMM: ctx^T (8x128) @ Wout_h, wave owns 4 of 8 col-tiles ====
    bfrag ac[4];
    #pragma unroll
    for (int ks = 0; ks < 4; ++ks)
        ac[ks] = (m16 < 8)
            ? *(const bfrag*)&lds[CTXK + plw*1024 + m16*128
                  + (((2*ks + (quad >> 1)) ^ (m16 & 3)) << 4) + (quad & 1)*8]
            : bzero();
    const short* Wo = Wout_pt + h * 16384;
    // output row permute: pat = pg*4+plw -> (bb,dd,hh,ww); p = quad*4+r
    const int pat = pg*4 + plw;
    const int bb2 = pat >> 5, rem = pat & 31;
    const int dd = rem >> 4, hh2 = (rem >> 2) & 3, ww2 = rem & 3;

    bfrag wbA[4], wbB[4];
    #pragma unroll
    for (int ks = 0; ks < 4; ++ks)
        wbA[ks] = *(const bfrag*)&Wo[(ih*64 + m16)*128 + ks*32 + q8];
    #pragma unroll 1
    for (int n = 0; n < 4; ++n) {
        const int ct = ih*4 + n;                // col-tile 0..7
        if (n < 3) {
            #pragma unroll
            for (int ks = 0; ks < 4; ++ks)
                wbB[ks] = *(const bfrag*)&Wo[((ct+1)*16 + m16)*128 + ks*32 + q8];
        }
        f32x4 cc2 = {0.f,0.f,0.f,0.f};
        __builtin_amdgcn_s_setprio(1);
        #pragma unroll
        for (int ks = 0; ks < 4; ++ks)
            cc2 = __builtin_amdgcn_mfma_f32_16x16x32_bf16(ac[ks], wbA[ks], cc2, 0,0,0);
        __builtin_amdgcn_s_setprio(0);
        if (quad < 2) {
            #pragma unroll
            for (int r = 0; r < 4; ++r) {
                const int orow = bb2*256
                    + ((((dd*2 + quad)*4 + hh2)*2 + (r >> 1))*4 + ww2)*2 + (r & 1);
                atomicAdd(&out[(size_t)orow*128 + ct*16 + m16], cc2[r]);
            }
        }
        #pragma unroll
        for (int ks = 0; ks < 4; ++ks)
            wbA[ks] = wbB[ks];
    }
}

extern "C" void kernel_launch(void* const* d_in, const int* in_sizes, int n_in,
                              void* d_out, int out_size, void* d_ws, size_t ws_size,
                              hipStream_t stream) {
    const float* emb  = (const float*)d_in[0];   // (512, 8, 128)
    const float* Wq   = (const float*)d_in[1];   // (128, 1024)
    const float* Wk   = (const float*)d_in[2];
    const float* Wv   = (const float*)d_in[3];
    const float* Wout = (const float*)d_in[4];   // (1024, 128)
    float* out = (float*)d_out;                  // 524288 floats

    short* Wp      = (short*)d_ws;               // 768 KB
    short* Wout_pt = Wp + 393216;                // 256 KB

    convertW<<<128, 256, 0, stream>>>(Wq, Wk, Wv, Wout, Wp, Wout_pt, out);
    attn4<<<1024, 512, 0, stream>>>(emb, Wp, Wout_pt, out);
}

// Round 16
// 120.307 us; speedup vs baseline: 1.2065x; 1.2065x over previous
//
#include <hip/hip_runtime.h>
#include <hip/hip_bf16.h>
#include <math.h>

// Self_Attention_Local R21: R20 + ONE delta: __launch_bounds__(512,8)->(512,6).
//   R20's work-preserving 8-wave split achieved 72% occupancy but the
//   8-waves/EU bound capped VGPR at 32 (< the ~75 live state) -> ~140MB/disp
//   scratch spill (FETCH 57.7MB, WRITE 104MB). R21 requests 6 waves/EU:
//   VGPR cap ~85 (fits the measured state), 3 blocks/CU (LDS 120<=160KB),
//   24 waves/CU = 1.5x R16 TLP with half the per-wave work.
//   Guards: FETCH ~5.5MB / WRITE ~16.4MB (spill-gone signature), VGPR 72-84.
//   KEPT: all of R20 (work-preserving 8-wave split, 4 barriers, XCD swizzle,
//   setprio, rotated out-GEMM, f2bf, R8 keys, 6-shuffle butterfly).
//   DEAD: cvt_pk asm (R17), i-split-by-block (R19), 8-waves/EU bound (R20).
//   QUARANTINED: gh-shortcut, cross-loop lookahead (R12).

typedef short bfrag __attribute__((ext_vector_type(8)));   // 8 bf16 = 4 VGPRs
typedef float f32x4 __attribute__((ext_vector_type(4)));

static __device__ __forceinline__ short f2bf(float x) {
    __hip_bfloat16 h = __float2bfloat16(x);
    return __builtin_bit_cast(short, h);
}
static __device__ __forceinline__ bfrag bzero() {
    bfrag z;
    #pragma unroll
    for (int j = 0; j < 8; ++j) z[j] = 0;
    return z;
}

// ---------------- convertW: 128 blocks ----------------
__global__ __launch_bounds__(256) void convertW(
    const float* __restrict__ Wq, const float* __restrict__ Wk,
    const float* __restrict__ Wv, const float* __restrict__ Wout,
    short* __restrict__ Wp, short* __restrict__ Wout_pt,
    float* __restrict__ out)
{
    __shared__ short lt[128 * 33];          // union: [32][129] or [128][33]
    const int b = blockIdx.x, t = threadIdx.x;

    // zero out: 524288 floats = 131072 float4 = 128 blocks x 1024
    {
        float4* o4 = (float4*)out;
        const int zb = b * 1024 + t;
        #pragma unroll
        for (int k = 0; k < 4; ++k)
            o4[zb + k * 256] = make_float4(0.f, 0.f, 0.f, 0.f);
    }

    if (b < 96) {
        const int x = b >> 5, h = (b >> 2) & 7, k0 = (b & 3) * 32;
        const float* W = (x == 0) ? Wq : (x == 1) ? Wk : Wv;
        #pragma unroll 4
        for (int rr = 0; rr < 16; ++rr) {
            const int k = rr * 2 + (t >> 7);          // 0..31
            const int i = t & 127;
            lt[k * 129 + i] = f2bf(W[(k0 + k) * 1024 + i * 8 + h]);
        }
        __syncthreads();
        short* dst = Wp + (x * 8 + h) * 16384;
        #pragma unroll
        for (int pp = 0; pp < 4; ++pp) {
            const int i  = pp * 32 + (t >> 3);
            const int kk = (t & 7) * 4;
            short4 v;
            v.x = lt[(kk + 0) * 129 + i]; v.y = lt[(kk + 1) * 129 + i];
            v.z = lt[(kk + 2) * 129 + i]; v.w = lt[(kk + 3) * 129 + i];
            *(short4*)&dst[i * 128 + k0 + kk] = v;
        }
    } else {
        const int b2 = b - 96, h = b2 >> 2, c0 = (b2 & 3) * 32;
        #pragma unroll 4
        for (int rr = 0; rr < 16; ++rr) {
            const int i = rr * 8 + (t >> 5);
            const int c = t & 31;
            lt[i * 33 + c] = f2bf(Wout[(i * 8 + h) * 128 + c0 + c]);
        }
        __syncthreads();
        short* dst = Wout_pt + h * 16384;
        #pragma unroll
        for (int pp = 0; pp < 4; ++pp) {
            const int c  = pp * 8 + (t >> 5);
            const int i0 = (t & 31) * 4;
            short4 v;
            v.x = lt[(i0 + 0) * 33 + c]; v.y = lt[(i0 + 1) * 33 + c];
            v.z = lt[(i0 + 2) * 33 + c]; v.w = lt[(i0 + 3) * 33 + c];
            *(short4*)&dst[(c0 + c) * 128 + i0] = v;
        }
    }
}

// ---------------- attn4 ----------------
// Block = (patch-group of 4, head), 512 threads = 8 waves.
// Wave w8: patch plw = w8>>1, i-half ih = w8&1.
// LDS zones (shorts), 40 KB (R16 layout, per-patch subregions +plw*1024):
//   QT [0..4095]      Qt[pl][i][p]    (dies -> ih=0 P chunks 0,1)
//   KT [4096..8191]   Kt[pl][j][p]    (live in band loop; CTX after bar3)
//   QN [8192..12287]  Q natural, swz  (dies -> ih=0 P chunks 2,3)
//   KN [12288..16383] K natural, swz  (dies -> ih=1 P chunks 0,1)
//   VS [16384..20479] V natural, swz  (dies -> ih=1 P chunks 2,3)
#define QT   0
#define KT   4096
#define QN   8192
#define KN   12288
#define VS   16384
#define CTXK 4096

__global__ __launch_bounds__(512, 6) void attn4(
    const float* __restrict__ emb,      // [4096][128] fp32
    const short* __restrict__ Wp,       // [3][8][128 i][128 k]
    const short* __restrict__ Wout_pt,  // [8][128 col][128 i]
    float* __restrict__ out)            // [4096][128] fp32, atomic target
{
    __shared__ short lds[20480];        // 40 KB -> 3 blocks/CU (VGPR-bound)
    const int bid = blockIdx.x;         // 0..1023
    // XCD-aware swizzle: heads of one patch-group share bid mod 8 -> same XCD
    const int pg  = bid & 127;          // patch group of 4
    const int h   = bid >> 7;           // head
    const int t   = threadIdx.x;        // 0..511
    const int w8   = t >> 6;            // wave 0..7
    const int plw  = w8 >> 1;           // patch 0..3
    const int ih   = w8 & 1;            // i-half
    const int lane = t & 63;
    const int m16  = lane & 15;
    const int quad = lane >> 4;
    const int q8   = quad * 8;

    // ================= QKV: (32x128) @ W_h (128x128) x3 =================
    // 24 i-tiles split 3 per wave; stores verbatim R16.
    {
        bfrag a[2][4];
        #pragma unroll
        for (int tm = 0; tm < 2; ++tm)
            #pragma unroll
            for (int ks = 0; ks < 4; ++ks) {
                const float* er = emb + (size_t)(pg*32 + tm*16 + m16) * 128 + ks*32 + q8;
                const float4 x0 = *(const float4*)er;
                const float4 x1 = *(const float4*)(er + 4);
                bfrag f;
                f[0]=f2bf(x0.x); f[1]=f2bf(x0.y); f[2]=f2bf(x0.z); f[3]=f2bf(x0.w);
                f[4]=f2bf(x1.x); f[5]=f2bf(x1.y); f[6]=f2bf(x1.z); f[7]=f2bf(x1.w);
                a[tm][ks] = f;
            }

        #pragma unroll
        for (int tt = 0; tt < 3; ++tt) {
            const int nt = w8 * 3 + tt;           // 0..23 = {q,k,v} x 8 i-tiles
            const int x  = nt >> 3;
            const int i0 = (nt & 7) * 16;
            const short* Wb = Wp + ((x*8 + h)*128 + i0 + m16) * 128;
            bfrag bb[4];
            #pragma unroll
            for (int ks = 0; ks < 4; ++ks)
                bb[ks] = *(const bfrag*)&Wb[ks*32 + q8];
            f32x4 c0 = {0.f,0.f,0.f,0.f}, c1 = {0.f,0.f,0.f,0.f};
            __builtin_amdgcn_s_setprio(1);
            #pragma unroll
            for (int ks = 0; ks < 4; ++ks) {
                c0 = __builtin_amdgcn_mfma_f32_16x16x32_bf16(a[0][ks], bb[ks], c0, 0,0,0);
                c1 = __builtin_amdgcn_mfma_f32_16x16x32_bf16(a[1][ks], bb[ks], c1, 0,0,0);
            }
            __builtin_amdgcn_s_setprio(0);
            #pragma unroll
            for (int tm = 0; tm < 2; ++tm) {
                const f32x4 cc = tm ? c1 : c0;
                const int mrow0 = tm*16 + quad*4;     // 4 consecutive tokens
                const int pl = mrow0 >> 3;            // local patch
                const int p0 = mrow0 & 7;             // 0 or 4
                const int col = i0 + m16;
                const int cb  = nt & 7;               // column block = i>>4
                if (x == 0) {
                    short4 v;
                    v.x = f2bf(cc[0]); v.y = f2bf(cc[1]);
                    v.z = f2bf(cc[2]); v.w = f2bf(cc[3]);
                    *(short4*)&lds[QT + pl*1024 + col*8 + p0] = v;   // Qt[i][p]
                    #pragma unroll
                    for (int r = 0; r < 4; ++r)       // Qn[p][i], block-swz
                        lds[QN + pl*1024 + (p0 + r)*128
                            + ((cb ^ ((p0 + r) & 3)) << 4) + m16] = f2bf(cc[r]);
                } else if (x == 1) {
                    short4 v;
                    v.x = f2bf(cc[0]); v.y = f2bf(cc[1]);
                    v.z = f2bf(cc[2]); v.w = f2bf(cc[3]);
                    *(short4*)&lds[KT + pl*1024 + col*8 + p0] = v;   // Kt[j][p]
                    #pragma unroll
                    for (int r = 0; r < 4; ++r)       // Kn[p][j], block-swz
                        lds[KN + pl*1024 + (p0 + r)*128
                            + ((cb ^ ((p0 + r) & 3)) << 4) + m16] = f2bf(cc[r]);
                } else {
                    // Vs[p][j], column-group swizzled -> conflict-free
                    const int g = ((cb ^ (((pl & 1) << 1) | (p0 >> 2))) << 4);
                    #pragma unroll
                    for (int r = 0; r < 4; ++r)
                        lds[VS + pl*1024 + (p0 + r)*128 + g + m16] = f2bf(cc[r]);
                }
            }
        }
    }
    __syncthreads();   // barrier 1: cross-wave QKV exchange

    // ===== stats via Grams (redundant per i-half pair; reads patch plw) ====
    float rs2, nbias;
    {
        bfrag gq[4], gk[4], gs[4], ones;
        #pragma unroll
        for (int j = 0; j < 8; ++j) ones[j] = (short)0x3F80;   // bf16 1.0
        #pragma unroll
        for (int ks = 0; ks < 4; ++ks) {
            const int bswz = (((2*ks + (quad >> 1)) ^ (m16 & 3)) << 4) + (quad & 1)*8;
            gq[ks] = (m16 < 8) ? *(const bfrag*)&lds[QN + plw*1024 + m16*128 + bswz] : bzero();
            gk[ks] = (m16 < 8) ? *(const bfrag*)&lds[KN + plw*1024 + m16*128 + bswz] : bzero();
            gs[ks] = (m16 < 8) ? *(const bfrag*)&lds[QN + plw*1024 + m16*128 + bswz]
                               : *(const bfrag*)&lds[KN + plw*1024 + (m16 - 8)*128 + bswz];
        }
        f32x4 cg = {0.f,0.f,0.f,0.f}, ch = {0.f,0.f,0.f,0.f}, cs = {0.f,0.f,0.f,0.f};
        __builtin_amdgcn_s_setprio(1);
        #pragma unroll
        for (int ks = 0; ks < 4; ++ks) {
            cg = __builtin_amdgcn_mfma_f32_16x16x32_bf16(gq[ks], gq[ks], cg, 0,0,0);
            ch = __builtin_amdgcn_mfma_f32_16x16x32_bf16(gk[ks], gk[ks], ch, 0,0,0);
            cs = __builtin_amdgcn_mfma_f32_16x16x32_bf16(gs[ks], ones,  cs, 0,0,0);
        }
        __builtin_amdgcn_s_setprio(0);
        float gh = 0.f, sp = 0.f;
        #pragma unroll
        for (int r = 0; r < 4; ++r) {
            gh = fmaf(cg[r], ch[r], gh);
            sp = fmaf(cs[r], __shfl_xor(cs[r], 32), sp);     // sQ[p]*sK[p]
        }
        sp += __shfl_xor(sp, 16);
        #pragma unroll
        for (int off = 1; off <= 32; off <<= 1)
            gh += __shfl_xor(gh, off);
        const float mean = sp * (1.f / 16384.f);
        const float var  = gh * (1.f / 16384.f) - mean * mean;
        rs2   = rsqrtf(var + 1e-5f) * 1.44269504f;           // fold log2(e)
        nbias = -mean * rs2;
    }

    // ===== hoist Qt B-frags (own i-half) and V A-frags (patch plw) ========
    bfrag bs[4], av[4];
    #pragma unroll
    for (int nt = 0; nt < 4; ++nt)
        bs[nt] = (quad == 0)
            ? *(const bfrag*)&lds[QT + plw*1024 + (ih*64 + nt*16 + m16)*8] : bzero();
    #pragma unroll
    for (int ks = 0; ks < 4; ++ks) {
        if (m16 < 8) {
            const int g = (((2*ks + (quad >> 1)) ^ (((plw & 1) << 1) | (m16 >> 2))) << 4);
            av[ks] = *(const bfrag*)&lds[VS + plw*1024 + m16*128 + g + (quad & 1)*8];
        } else if (m16 == 8) {                 // ones ROW -> C[8][i] = rowsum_i
            bfrag o;
            #pragma unroll
            for (int j = 0; j < 8; ++j) o[j] = (short)0x3F80;
            av[ks] = o;
        } else
            av[ks] = bzero();
    }
    __syncthreads();   // barrier 2: zones read by sibling waves -> P overlay ok

    // ===== band loop: 8 bands, 4 i-tiles per wave; P in own dead zones =====
    // P chunk (ih, nt): ih=0 -> {QT,QN}[plw], ih=1 -> {KN,VS}[plw];
    // [16 i][32 j] = 512 shorts; formulas verbatim R16.
    const int key2 = m16 >> 2;
    const int rowoff = m16 * 32;
    f32x4 cc[4];
    #pragma unroll
    for (int nt = 0; nt < 4; ++nt) cc[nt] = (f32x4){0.f,0.f,0.f,0.f};

    #pragma unroll
    for (int ks = 0; ks < 4; ++ks) {
        #pragma unroll
        for (int jb = 0; jb < 2; ++jb) {
            const int band = ks*2 + jb;
            const bfrag amk = (quad == 0)
                ? *(const bfrag*)&lds[KT + plw*1024 + (band*16 + m16)*8] : bzero();
            const int tw = (((jb*2 + (quad >> 1)) ^ key2) << 3) + (quad & 1)*4;
            #pragma unroll
            for (int nt = 0; nt < 4; ++nt) {
                const int zb = (ih == 0) ? ((nt >> 1) ? QN : QT)
                                         : ((nt >> 1) ? VS : KN);
                f32x4 z = {0.f,0.f,0.f,0.f};
                __builtin_amdgcn_s_setprio(1);
                const f32x4 s4 = __builtin_amdgcn_mfma_f32_16x16x32_bf16(amk, bs[nt], z, 0,0,0);
                __builtin_amdgcn_s_setprio(0);
                short4 v;
                v.x = f2bf(__builtin_amdgcn_exp2f(fmaf(s4[0], rs2, nbias)));
                v.y = f2bf(__builtin_amdgcn_exp2f(fmaf(s4[1], rs2, nbias)));
                v.z = f2bf(__builtin_amdgcn_exp2f(fmaf(s4[2], rs2, nbias)));
                v.w = f2bf(__builtin_amdgcn_exp2f(fmaf(s4[3], rs2, nbias)));
                *(short4*)&lds[zb + plw*1024 + (nt & 1)*512 + rowoff + tw] = v;
            }
        }
        __builtin_amdgcn_s_setprio(1);
        #pragma unroll
        for (int nt = 0; nt < 4; ++nt) {
            const int zb = (ih == 0) ? ((nt >> 1) ? QN : QT)
                                     : ((nt >> 1) ? VS : KN);
            const bfrag bp = *(const bfrag*)
                &lds[zb + plw*1024 + (nt & 1)*512 + rowoff + ((quad ^ key2) << 3)];
            cc[nt] = __builtin_amdgcn_mfma_f32_16x16x32_bf16(av[ks], bp, cc[nt], 0,0,0);
        }
        __builtin_amdgcn_s_setprio(0);
    }

    __syncthreads();   // barrier 3: both waves of plw done with KT -> CTX overlay

    // ===== normalize once; ctx[p][i] -> KT[plw] (global i-tile ih*4+nt) ====
    #pragma unroll
    for (int nt = 0; nt < 4; ++nt) {
        const float s  = __shfl(cc[nt][0], 32 + m16);   // C[8][i] from quad-2
        const float is = 1.0f / s;
        if (quad < 2) {
            #pragma unroll
            for (int r = 0; r < 4; ++r) {
                const int p = quad*4 + r;
                lds[CTXK + plw*1024 + p*128 + (((ih*4 + nt) ^ (p & 3)) << 4) + m16] =
                    f2bf(cc[nt][r] * is);
            }
        }
    }
    __syncthreads();   // barrier 4: full CTX visible to both waves of plw

    // ===== out-GEMM: ctx^T (8x128) @ Wout_h, wave owns 4 of 8 col-tiles ====
    bfrag ac[4];
    #pragma unroll
    for (int ks = 0; ks < 4; ++ks)
        ac[ks] = (m16 < 8)
            ? *(const bfrag*)&lds[CTXK + plw*1024 + m16*128
                  + (((2*ks + (quad >> 1)) ^ (m16 & 3)) << 4) + (quad & 1)*8]
            : bzero();
    const short* Wo = Wout_pt + h * 16384;
    // output row permute: pat = pg*4+plw -> (bb,dd,hh,ww); p = quad*4+r
    const int pat = pg*4 + plw;
    const int bb2 = pat >> 5, rem = pat & 31;
    const int dd = rem >> 4, hh2 = (rem >> 2) & 3, ww2 = rem & 3;

    bfrag wbA[4], wbB[4];
    #pragma unroll
    for (int ks = 0; ks < 4; ++ks)
        wbA[ks] = *(const bfrag*)&Wo[(ih*64 + m16)*128 + ks*32 + q8];
    #pragma unroll 1
    for (int n = 0; n < 4; ++n) {
        const int ct = ih*4 + n;                // col-tile 0..7
        if (n < 3) {
            #pragma unroll
            for (int ks = 0; ks < 4; ++ks)
                wbB[ks] = *(const bfrag*)&Wo[((ct+1)*16 + m16)*128 + ks*32 + q8];
        }
        f32x4 cc2 = {0.f,0.f,0.f,0.f};
        __builtin_amdgcn_s_setprio(1);
        #pragma unroll
        for (int ks = 0; ks < 4; ++ks)
            cc2 = __builtin_amdgcn_mfma_f32_16x16x32_bf16(ac[ks], wbA[ks], cc2, 0,0,0);
        __builtin_amdgcn_s_setprio(0);
        if (quad < 2) {
            #pragma unroll
            for (int r = 0; r < 4; ++r) {
                const int orow = bb2*256
                    + ((((dd*2 + quad)*4 + hh2)*2 + (r >> 1))*4 + ww2)*2 + (r & 1);
                atomicAdd(&out[(size_t)orow*128 + ct*16 + m16], cc2[r]);
            }
        }
        #pragma unroll
        for (int ks = 0; ks < 4; ++ks)
            wbA[ks] = wbB[ks];
    }
}

extern "C" void kernel_launch(void* const* d_in, const int* in_sizes, int n_in,
                              void* d_out, int out_size, void* d_ws, size_t ws_size,
                              hipStream_t stream) {
    const float* emb  = (const float*)d_in[0];   // (512, 8, 128)
    const float* Wq   = (const float*)d_in[1];   // (128, 1024)
    const float* Wk   = (const float*)d_in[2];
    const float* Wv   = (const float*)d_in[3];
    const float* Wout = (const float*)d_in[4];   // (1024, 128)
    float* out = (float*)d_out;                  // 524288 floats

    short* Wp      = (short*)d_ws;               // 768 KB
    short* Wout_pt = Wp + 393216;                // 256 KB

    convertW<<<128, 256, 0, stream>>>(Wq, Wk, Wv, Wout, Wp, Wout_pt, out);
    attn4<<<1024, 512, 0, stream>>>(emb, Wp, Wout_pt, out);
}

// Round 17
// 112.768 us; speedup vs baseline: 1.2872x; 1.0669x over previous
//
#include <hip/hip_runtime.h>
#include <hip/hip_bf16.h>
#include <math.h>

// Self_Attention_Local R22: R21 + ONE delta: drop the launch_bounds register
//   cap: __launch_bounds__(512,6) -> __launch_bounds__(512).
//   R20/R21 evidence: allocated arch-VGPR == half the bound's budget
//   (cap 64->32, cap 85->40) -- the arch/acc split halves the usable file,
//   so the min-waves arg force-spilled (~140MB then ~12MB per dispatch).
//   R22 lets the allocator take what the ~75-VGPR state needs (no spill)
//   and lets occupancy follow: ~80 VGPR -> 5-6 waves/SIMD -> 16-24 waves/CU.
//   Guards: VGPR 72-96, FETCH ~5.5MB, WRITE ~16.4MB (spill-gone signature).
//   If occupancy quantizes to 16 waves/CU the occupancy path is closed and
//   R16 is the terminal kernel.
//   KEPT: all of R21 (work-preserving 8-wave split, 4 barriers, XCD swizzle,
//   setprio, rotated out-GEMM, f2bf, R8 keys, 6-shuffle butterfly).
//   DEAD: cvt_pk asm (R17), i-split-by-block (R19), forced min-waves
//   (R20/R21). QUARANTINED: gh-shortcut, cross-loop lookahead (R12).

typedef short bfrag __attribute__((ext_vector_type(8)));   // 8 bf16 = 4 VGPRs
typedef float f32x4 __attribute__((ext_vector_type(4)));

static __device__ __forceinline__ short f2bf(float x) {
    __hip_bfloat16 h = __float2bfloat16(x);
    return __builtin_bit_cast(short, h);
}
static __device__ __forceinline__ bfrag bzero() {
    bfrag z;
    #pragma unroll
    for (int j = 0; j < 8; ++j) z[j] = 0;
    return z;
}

// ---------------- convertW: 128 blocks ----------------
__global__ __launch_bounds__(256) void convertW(
    const float* __restrict__ Wq, const float* __restrict__ Wk,
    const float* __restrict__ Wv, const float* __restrict__ Wout,
    short* __restrict__ Wp, short* __restrict__ Wout_pt,
    float* __restrict__ out)
{
    __shared__ short lt[128 * 33];          // union: [32][129] or [128][33]
    const int b = blockIdx.x, t = threadIdx.x;

    // zero out: 524288 floats = 131072 float4 = 128 blocks x 1024
    {
        float4* o4 = (float4*)out;
        const int zb = b * 1024 + t;
        #pragma unroll
        for (int k = 0; k < 4; ++k)
            o4[zb + k * 256] = make_float4(0.f, 0.f, 0.f, 0.f);
    }

    if (b < 96) {
        const int x = b >> 5, h = (b >> 2) & 7, k0 = (b & 3) * 32;
        const float* W = (x == 0) ? Wq : (x == 1) ? Wk : Wv;
        #pragma unroll 4
        for (int rr = 0; rr < 16; ++rr) {
            const int k = rr * 2 + (t >> 7);          // 0..31
            const int i = t & 127;
            lt[k * 129 + i] = f2bf(W[(k0 + k) * 1024 + i * 8 + h]);
        }
        __syncthreads();
        short* dst = Wp + (x * 8 + h) * 16384;
        #pragma unroll
        for (int pp = 0; pp < 4; ++pp) {
            const int i  = pp * 32 + (t >> 3);
            const int kk = (t & 7) * 4;
            short4 v;
            v.x = lt[(kk + 0) * 129 + i]; v.y = lt[(kk + 1) * 129 + i];
            v.z = lt[(kk + 2) * 129 + i]; v.w = lt[(kk + 3) * 129 + i];
            *(short4*)&dst[i * 128 + k0 + kk] = v;
        }
    } else {
        const int b2 = b - 96, h = b2 >> 2, c0 = (b2 & 3) * 32;
        #pragma unroll 4
        for (int rr = 0; rr < 16; ++rr) {
            const int i = rr * 8 + (t >> 5);
            const int c = t & 31;
            lt[i * 33 + c] = f2bf(Wout[(i * 8 + h) * 128 + c0 + c]);
        }
        __syncthreads();
        short* dst = Wout_pt + h * 16384;
        #pragma unroll
        for (int pp = 0; pp < 4; ++pp) {
            const int c  = pp * 8 + (t >> 5);
            const int i0 = (t & 31) * 4;
            short4 v;
            v.x = lt[(i0 + 0) * 33 + c]; v.y = lt[(i0 + 1) * 33 + c];
            v.z = lt[(i0 + 2) * 33 + c]; v.w = lt[(i0 + 3) * 33 + c];
            *(short4*)&dst[(c0 + c) * 128 + i0] = v;
        }
    }
}

// ---------------- attn4 ----------------
// Block = (patch-group of 4, head), 512 threads = 8 waves.
// Wave w8: patch plw = w8>>1, i-half ih = w8&1.
// LDS zones (shorts), 40 KB (R16 layout, per-patch subregions +plw*1024):
//   QT [0..4095]      Qt[pl][i][p]    (dies -> ih=0 P chunks 0,1)
//   KT [4096..8191]   Kt[pl][j][p]    (live in band loop; CTX after bar3)
//   QN [8192..12287]  Q natural, swz  (dies -> ih=0 P chunks 2,3)
//   KN [12288..16383] K natural, swz  (dies -> ih=1 P chunks 0,1)
//   VS [16384..20479] V natural, swz  (dies -> ih=1 P chunks 2,3)
#define QT   0
#define KT   4096
#define QN   8192
#define KN   12288
#define VS   16384
#define CTXK 4096

__global__ __launch_bounds__(512) void attn4(
    const float* __restrict__ emb,      // [4096][128] fp32
    const short* __restrict__ Wp,       // [3][8][128 i][128 k]
    const short* __restrict__ Wout_pt,  // [8][128 col][128 i]
    float* __restrict__ out)            // [4096][128] fp32, atomic target
{
    __shared__ short lds[20480];        // 40 KB
    const int bid = blockIdx.x;         // 0..1023
    // XCD-aware swizzle: heads of one patch-group share bid mod 8 -> same XCD
    const int pg  = bid & 127;          // patch group of 4
    const int h   = bid >> 7;           // head
    const int t   = threadIdx.x;        // 0..511
    const int w8   = t >> 6;            // wave 0..7
    const int plw  = w8 >> 1;           // patch 0..3
    const int ih   = w8 & 1;            // i-half
    const int lane = t & 63;
    const int m16  = lane & 15;
    const int quad = lane >> 4;
    const int q8   = quad * 8;

    // ================= QKV: (32x128) @ W_h (128x128) x3 =================
    // 24 i-tiles split 3 per wave; stores verbatim R16.
    {
        bfrag a[2][4];
        #pragma unroll
        for (int tm = 0; tm < 2; ++tm)
            #pragma unroll
            for (int ks = 0; ks < 4; ++ks) {
                const float* er = emb + (size_t)(pg*32 + tm*16 + m16) * 128 + ks*32 + q8;
                const float4 x0 = *(const float4*)er;
                const float4 x1 = *(const float4*)(er + 4);
                bfrag f;
                f[0]=f2bf(x0.x); f[1]=f2bf(x0.y); f[2]=f2bf(x0.z); f[3]=f2bf(x0.w);
                f[4]=f2bf(x1.x); f[5]=f2bf(x1.y); f[6]=f2bf(x1.z); f[7]=f2bf(x1.w);
                a[tm][ks] = f;
            }

        #pragma unroll
        for (int tt = 0; tt < 3; ++tt) {
            const int nt = w8 * 3 + tt;           // 0..23 = {q,k,v} x 8 i-tiles
            const int x  = nt >> 3;
            const int i0 = (nt & 7) * 16;
            const short* Wb = Wp + ((x*8 + h)*128 + i0 + m16) * 128;
            bfrag bb[4];
            #pragma unroll
            for (int ks = 0; ks < 4; ++ks)
                bb[ks] = *(const bfrag*)&Wb[ks*32 + q8];
            f32x4 c0 = {0.f,0.f,0.f,0.f}, c1 = {0.f,0.f,0.f,0.f};
            __builtin_amdgcn_s_setprio(1);
            #pragma unroll
            for (int ks = 0; ks < 4; ++ks) {
                c0 = __builtin_amdgcn_mfma_f32_16x16x32_bf16(a[0][ks], bb[ks], c0, 0,0,0);
                c1 = __builtin_amdgcn_mfma_f32_16x16x32_bf16(a[1][ks], bb[ks], c1, 0,0,0);
            }
            __builtin_amdgcn_s_setprio(0);
            #pragma unroll
            for (int tm = 0; tm < 2; ++tm) {
                const f32x4 cc = tm ? c1 : c0;
                const int mrow0 = tm*16 + quad*4;     // 4 consecutive tokens
                const int pl = mrow0 >> 3;            // local patch
                const int p0 = mrow0 & 7;             // 0 or 4
                const int col = i0 + m16;
                const int cb  = nt & 7;               // column block = i>>4
                if (x == 0) {
                    short4 v;
                    v.x = f2bf(cc[0]); v.y = f2bf(cc[1]);
                    v.z = f2bf(cc[2]); v.w = f2bf(cc[3]);
                    *(short4*)&lds[QT + pl*1024 + col*8 + p0] = v;   // Qt[i][p]
                    #pragma unroll
                    for (int r = 0; r < 4; ++r)       // Qn[p][i], block-swz
                        lds[QN + pl*1024 + (p0 + r)*128
                            + ((cb ^ ((p0 + r) & 3)) << 4) + m16] = f2bf(cc[r]);
                } else if (x == 1) {
                    short4 v;
                    v.x = f2bf(cc[0]); v.y = f2bf(cc[1]);
                    v.z = f2bf(cc[2]); v.w = f2bf(cc[3]);
                    *(short4*)&lds[KT + pl*1024 + col*8 + p0] = v;   // Kt[j][p]
                    #pragma unroll
                    for (int r = 0; r < 4; ++r)       // Kn[p][j], block-swz
                        lds[KN + pl*1024 + (p0 + r)*128
                            + ((cb ^ ((p0 + r) & 3)) << 4) + m16] = f2bf(cc[r]);
                } else {
                    // Vs[p][j], column-group swizzled -> conflict-free
                    const int g = ((cb ^ (((pl & 1) << 1) | (p0 >> 2))) << 4);
                    #pragma unroll
                    for (int r = 0; r < 4; ++r)
                        lds[VS + pl*1024 + (p0 + r)*128 + g + m16] = f2bf(cc[r]);
                }
            }
        }
    }
    __syncthreads();   // barrier 1: cross-wave QKV exchange

    // ===== stats via Grams (redundant per i-half pair; reads patch plw) ====
    float rs2, nbias;
    {
        bfrag gq[4], gk[4], gs[4], ones;
        #pragma unroll
        for (int j = 0; j < 8; ++j) ones[j] = (short)0x3F80;   // bf16 1.0
        #pragma unroll
        for (int ks = 0; ks < 4; ++ks) {
            const int bswz = (((2*ks + (quad >> 1)) ^ (m16 & 3)) << 4) + (quad & 1)*8;
            gq[ks] = (m16 < 8) ? *(const bfrag*)&lds[QN + plw*1024 + m16*128 + bswz] : bzero();
            gk[ks] = (m16 < 8) ? *(const bfrag*)&lds[KN + plw*1024 + m16*128 + bswz] : bzero();
            gs[ks] = (m16 < 8) ? *(const bfrag*)&lds[QN + plw*1024 + m16*128 + bswz]
                               : *(const bfrag*)&lds[KN + plw*1024 + (m16 - 8)*128 + bswz];
        }
        f32x4 cg = {0.f,0.f,0.f,0.f}, ch = {0.f,0.f,0.f,0.f}, cs = {0.f,0.f,0.f,0.f};
        __builtin_amdgcn_s_setprio(1);
        #pragma unroll
        for (int ks = 0; ks < 4; ++ks) {
            cg = __builtin_amdgcn_mfma_f32_16x16x32_bf16(gq[ks], gq[ks], cg, 0,0,0);
            ch = __builtin_amdgcn_mfma_f32_16x16x32_bf16(gk[ks], gk[ks], ch, 0,0,0);
            cs = __builtin_amdgcn_mfma_f32_16x16x32_bf16(gs[ks], ones,  cs, 0,0,0);
        }
        __builtin_amdgcn_s_setprio(0);
        float gh = 0.f, sp = 0.f;
        #pragma unroll
        for (int r = 0; r < 4; ++r) {
            gh = fmaf(cg[r], ch[r], gh);
            sp = fmaf(cs[r], __shfl_xor(cs[r], 32), sp);     // sQ[p]*sK[p]
        }
        sp += __shfl_xor(sp, 16);
        #pragma unroll
        for (int off = 1; off <= 32; off <<= 1)
            gh += __shfl_xor(gh, off);
        const float mean = sp * (1.f / 16384.f);
        const float var  = gh * (1.f / 16384.f) - mean * mean;
        rs2   = rsqrtf(var + 1e-5f) * 1.44269504f;           // fold log2(e)
        nbias = -mean * rs2;
    }

    // ===== hoist Qt B-frags (own i-half) and V A-frags (patch plw) ========
    bfrag bs[4], av[4];
    #pragma unroll
    for (int nt = 0; nt < 4; ++nt)
        bs[nt] = (quad == 0)
            ? *(const bfrag*)&lds[QT + plw*1024 + (ih*64 + nt*16 + m16)*8] : bzero();
    #pragma unroll
    for (int ks = 0; ks < 4; ++ks) {
        if (m16 < 8) {
            const int g = (((2*ks + (quad >> 1)) ^ (((plw & 1) << 1) | (m16 >> 2))) << 4);
            av[ks] = *(const bfrag*)&lds[VS + plw*1024 + m16*128 + g + (quad & 1)*8];
        } else if (m16 == 8) {                 // ones ROW -> C[8][i] = rowsum_i
            bfrag o;
            #pragma unroll
            for (int j = 0; j < 8; ++j) o[j] = (short)0x3F80;
            av[ks] = o;
        } else
            av[ks] = bzero();
    }
    __syncthreads();   // barrier 2: zones read by sibling waves -> P overlay ok

    // ===== band loop: 8 bands, 4 i-tiles per wave; P in own dead zones =====
    // P chunk (ih, nt): ih=0 -> {QT,QN}[plw], ih=1 -> {KN,VS}[plw];
    // [16 i][32 j] = 512 shorts; formulas verbatim R16.
    const int key2 = m16 >> 2;
    const int rowoff = m16 * 32;
    f32x4 cc[4];
    #pragma unroll
    for (int nt = 0; nt < 4; ++nt) cc[nt] = (f32x4){0.f,0.f,0.f,0.f};

    #pragma unroll
    for (int ks = 0; ks < 4; ++ks) {
        #pragma unroll
        for (int jb = 0; jb < 2; ++jb) {
            const int band = ks*2 + jb;
            const bfrag amk = (quad == 0)
                ? *(const bfrag*)&lds[KT + plw*1024 + (band*16 + m16)*8] : bzero();
            const int tw = (((jb*2 + (quad >> 1)) ^ key2) << 3) + (quad & 1)*4;
            #pragma unroll
            for (int nt = 0; nt < 4; ++nt) {
                const int zb = (ih == 0) ? ((nt >> 1) ? QN : QT)
                                         : ((nt >> 1) ? VS : KN);
                f32x4 z = {0.f,0.f,0.f,0.f};
                __builtin_amdgcn_s_setprio(1);
                const f32x4 s4 = __builtin_amdgcn_mfma_f32_16x16x32_bf16(amk, bs[nt], z, 0,0,0);
                __builtin_amdgcn_s_setprio(0);
                short4 v;
                v.x = f2bf(__builtin_amdgcn_exp2f(fmaf(s4[0], rs2, nbias)));
                v.y = f2bf(__builtin_amdgcn_exp2f(fmaf(s4[1], rs2, nbias)));
                v.z = f2bf(__builtin_amdgcn_exp2f(fmaf(s4[2], rs2, nbias)));
                v.w = f2bf(__builtin_amdgcn_exp2f(fmaf(s4[3], rs2, nbias)));
                *(short4*)&lds[zb + plw*1024 + (nt & 1)*512 + rowoff + tw] = v;
            }
        }
        __builtin_amdgcn_s_setprio(1);
        #pragma unroll
        for (int nt = 0; nt < 4; ++nt) {
            const int zb = (ih == 0) ? ((nt >> 1) ? QN : QT)
                                     : ((nt >> 1) ? VS : KN);
            const bfrag bp = *(const bfrag*)
                &lds[zb + plw*1024 + (nt & 1)*512 + rowoff + ((quad ^ key2) << 3)];
            cc[nt] = __builtin_amdgcn_mfma_f32_16x16x32_bf16(av[ks], bp, cc[nt], 0,0,0);
        }
        __builtin_amdgcn_s_setprio(0);
    }

    __syncthreads();   // barrier 3: both waves of plw done with KT -> CTX overlay

    // ===== normalize once; ctx[p][i] -> KT[plw] (global i-tile ih*4+nt) ====
    #pragma unroll
    for (int nt = 0; nt < 4; ++nt) {
        const float s  = __shfl(cc[nt][0], 32 + m16);   // C[8][i] from quad-2
        const float is = 1.0f / s;
        if (quad < 2) {
            #pragma unroll
            for (int r = 0; r < 4; ++r) {
                const int p = quad*4 + r;
                lds[CTXK + plw*1024 + p*128 + (((ih*4 + nt) ^ (p & 3)) << 4) + m16] =
                    f2bf(cc[nt][r] * is);
            }
        }
    }
    __syncthreads();   // barrier 4: full CTX visible to both waves of plw

    // ===== out-GEMM: ctx^T (8x128) @ Wout_h, wave owns 4 of 8 col-tiles ====
    bfrag ac[4];
    #pragma unroll
    for (int ks = 0; ks < 4; ++ks)
        ac[ks] = (m16 < 8)
            ? *(const bfrag*)&lds[CTXK + plw*1024 + m16*128
                  + (((2*ks + (quad >> 1)) ^ (m16 & 3)) << 4) + (quad & 1)*8]
            : bzero();
    const short* Wo = Wout_pt + h * 16384;
    // output row permute: pat = pg*4+plw -> (bb,dd,hh,ww); p = quad*4+r
    const int pat = pg*4 + plw;
    const int bb2 = pat >> 5, rem = pat & 31;
    const int dd = rem >> 4, hh2 = (rem >> 2) & 3, ww2 = rem & 3;

    bfrag wbA[4], wbB[4];
    #pragma unroll
    for (int ks = 0; ks < 4; ++ks)
        wbA[ks] = *(const bfrag*)&Wo[(ih*64 + m16)*128 + ks*32 + q8];
    #pragma unroll 1
    for (int n = 0; n < 4; ++n) {
        const int ct = ih*4 + n;                // col-tile 0..7
        if (n < 3) {
            #pragma unroll
            for (int ks = 0; ks < 4; ++ks)
                wbB[ks] = *(const bfrag*)&Wo[((ct+1)*16 + m16)*128 + ks*32 + q8];
        }
        f32x4 cc2 = {0.f,0.f,0.f,0.f};
        __builtin_amdgcn_s_setprio(1);
        #pragma unroll
        for (int ks = 0; ks < 4; ++ks)
            cc2 = __builtin_amdgcn_mfma_f32_16x16x32_bf16(ac[ks], wbA[ks], cc2, 0,0,0);
        __builtin_amdgcn_s_setprio(0);
        if (quad < 2) {
            #pragma unroll
            for (int r = 0; r < 4; ++r) {
                const int orow = bb2*256
                    + ((((dd*2 + quad)*4 + hh2)*2 + (r >> 1))*4 + ww2)*2 + (r & 1);
                atomicAdd(&out[(size_t)orow*128 + ct*16 + m16], cc2[r]);
            }
        }
        #pragma unroll
        for (int ks = 0; ks < 4; ++ks)
            wbA[ks] = wbB[ks];
    }
}

extern "C" void kernel_launch(void* const* d_in, const int* in_sizes, int n_in,
                              void* d_out, int out_size, void* d_ws, size_t ws_size,
                              hipStream_t stream) {
    const float* emb  = (const float*)d_in[0];   // (512, 8, 128)
    const float* Wq   = (const float*)d_in[1];   // (128, 1024)
    const float* Wk   = (const float*)d_in[2];
    const float* Wv   = (const float*)d_in[3];
    const float* Wout = (const float*)d_in[4];   // (1024, 128)
    float* out = (float*)d_out;                  // 524288 floats

    short* Wp      = (short*)d_ws;               // 768 KB
    short* Wout_pt = Wp + 393216;                // 256 KB

    convertW<<<128, 256, 0, stream>>>(Wq, Wk, Wv, Wout, Wp, Wout_pt, out);
    attn4<<<1024, 512, 0, stream>>>(emb, Wp, Wout_pt, out);
}

// Round 18
// 101.632 us; speedup vs baseline: 1.4282x; 1.1096x over previous
//
#include <hip/hip_runtime.h>
#include <hip/hip_bf16.h>
#include <math.h>

// Self_Attention_Local R23 = R16 verbatim (terminal revert; session best
//   101.2us total, attn4 42.0us).
//   The R19-R22 occupancy excursion is closed: with clean registers (R22:
//   no spill, VGPR 48) the 8-wave split is still 23% slower than this
//   4-wave structure -- barrier lockstep + duplicated stats + halved
//   per-wave ILP exceed the (unrealized) TLP gain.
//   Banked wins: transposed scores + b64 P (R8), atomic head-fusion (R7),
//   rotated out-GEMM prefetch (R13), barrier-2 elimination (R14), XCD
//   swizzle (R15, FETCH 8.8->5.3MB), setprio (R16).
//   Convicted/dead: v_cvt_pk_bf16_f32 asm (R17 isolation), forced
//   min-waves launch_bounds (R20/R21 spill), i-split decompositions
//   (R19/R22), cross-loop lookahead regs (R12 spill), gh-shortcut
//   (quarantined, R10).
//   Known plateau: all pipes <30% busy, latency-bound at 16 waves/CU;
//   remaining ~58us of total is harness overhead (workspace re-poisoning
//   fill + launch gaps), not kernel-addressable.

typedef short bfrag __attribute__((ext_vector_type(8)));   // 8 bf16 = 4 VGPRs
typedef float f32x4 __attribute__((ext_vector_type(4)));

static __device__ __forceinline__ short f2bf(float x) {
    __hip_bfloat16 h = __float2bfloat16(x);
    return __builtin_bit_cast(short, h);
}
static __device__ __forceinline__ bfrag bzero() {
    bfrag z;
    #pragma unroll
    for (int j = 0; j < 8; ++j) z[j] = 0;
    return z;
}

// ---------------- convertW: 128 blocks ----------------
__global__ __launch_bounds__(256) void convertW(
    const float* __restrict__ Wq, const float* __restrict__ Wk,
    const float* __restrict__ Wv, const float* __restrict__ Wout,
    short* __restrict__ Wp, short* __restrict__ Wout_pt,
    float* __restrict__ out)
{
    __shared__ short lt[128 * 33];          // union: [32][129] or [128][33]
    const int b = blockIdx.x, t = threadIdx.x;

    // zero out: 524288 floats = 131072 float4 = 128 blocks x 1024
    {
        float4* o4 = (float4*)out;
        const int zb = b * 1024 + t;
        #pragma unroll
        for (int k = 0; k < 4; ++k)
            o4[zb + k * 256] = make_float4(0.f, 0.f, 0.f, 0.f);
    }

    if (b < 96) {
        const int x = b >> 5, h = (b >> 2) & 7, k0 = (b & 3) * 32;
        const float* W = (x == 0) ? Wq : (x == 1) ? Wk : Wv;
        #pragma unroll 4
        for (int rr = 0; rr < 16; ++rr) {
            const int k = rr * 2 + (t >> 7);          // 0..31
            const int i = t & 127;
            lt[k * 129 + i] = f2bf(W[(k0 + k) * 1024 + i * 8 + h]);
        }
        __syncthreads();
        short* dst = Wp + (x * 8 + h) * 16384;
        #pragma unroll
        for (int pp = 0; pp < 4; ++pp) {
            const int i  = pp * 32 + (t >> 3);
            const int kk = (t & 7) * 4;
            short4 v;
            v.x = lt[(kk + 0) * 129 + i]; v.y = lt[(kk + 1) * 129 + i];
            v.z = lt[(kk + 2) * 129 + i]; v.w = lt[(kk + 3) * 129 + i];
            *(short4*)&dst[i * 128 + k0 + kk] = v;
        }
    } else {
        const int b2 = b - 96, h = b2 >> 2, c0 = (b2 & 3) * 32;
        #pragma unroll 4
        for (int rr = 0; rr < 16; ++rr) {
            const int i = rr * 8 + (t >> 5);
            const int c = t & 31;
            lt[i * 33 + c] = f2bf(Wout[(i * 8 + h) * 128 + c0 + c]);
        }
        __syncthreads();
        short* dst = Wout_pt + h * 16384;
        #pragma unroll
        for (int pp = 0; pp < 4; ++pp) {
            const int c  = pp * 8 + (t >> 5);
            const int i0 = (t & 31) * 4;
            short4 v;
            v.x = lt[(i0 + 0) * 33 + c]; v.y = lt[(i0 + 1) * 33 + c];
            v.z = lt[(i0 + 2) * 33 + c]; v.w = lt[(i0 + 3) * 33 + c];
            *(short4*)&dst[(c0 + c) * 128 + i0] = v;
        }
    }
}

// ---------------- attn4 ----------------
// LDS zones (shorts), 40 KB:
//   QT [0..4095]      Qt[pl][i][p]    (own subregion dies -> P chunk 0)
//   KT [4096..8191]   Kt[pl][j][p]    (live through band loop; own CTX after)
//   QN [8192..12287]  Q natural, swz  (own subregion dies -> P chunk 1)
//   KN [12288..16383] K natural, swz  (own subregion dies -> P chunk 2)
//   VS [16384..20479] V natural, swz  (own subregion dies -> P chunk 3)
// P per wave: 4 chunks of 1024 shorts in the wave's OWN subregions.
#define QT   0
#define KT   4096
#define QN   8192
#define KN   12288
#define VS   16384
#define CTXK 4096

__global__ __launch_bounds__(256, 4) void attn4(
    const float* __restrict__ emb,      // [4096][128] fp32
    const short* __restrict__ Wp,       // [3][8][128 i][128 k]
    const short* __restrict__ Wout_pt,  // [8][128 col][128 i]
    float* __restrict__ out)            // [4096][128] fp32, atomic target
{
    __shared__ short lds[20480];        // 40 KB
    const int bid = blockIdx.x;         // 0..1023
    // XCD-aware swizzle: heads of one patch-group share bid mod 8 -> same XCD
    const int pg  = bid & 127;          // patch group of 4
    const int h   = bid >> 7;           // head
    const int t   = threadIdx.x;
    const int w    = t >> 6;            // wave 0..3 (owns patch pl = w)
    const int lane = t & 63;
    const int m16  = lane & 15;
    const int quad = lane >> 4;
    const int q8   = quad * 8;

    // ================= QKV: (32x128) @ W_h (128x128) x3 =================
    {
        bfrag a[2][4];
        #pragma unroll
        for (int tm = 0; tm < 2; ++tm)
            #pragma unroll
            for (int ks = 0; ks < 4; ++ks) {
                const float* er = emb + (size_t)(pg*32 + tm*16 + m16) * 128 + ks*32 + q8;
                const float4 x0 = *(const float4*)er;
                const float4 x1 = *(const float4*)(er + 4);
                bfrag f;
                f[0]=f2bf(x0.x); f[1]=f2bf(x0.y); f[2]=f2bf(x0.z); f[3]=f2bf(x0.w);
                f[4]=f2bf(x1.x); f[5]=f2bf(x1.y); f[6]=f2bf(x1.z); f[7]=f2bf(x1.w);
                a[tm][ks] = f;
            }

        #pragma unroll
        for (int tt = 0; tt < 6; ++tt) {
            const int nt = w * 6 + tt;            // 0..23 = {q,k,v} x 8 i-tiles
            const int x  = nt >> 3;
            const int i0 = (nt & 7) * 16;
            const short* Wb = Wp + ((x*8 + h)*128 + i0 + m16) * 128;
            bfrag bb[4];
            #pragma unroll
            for (int ks = 0; ks < 4; ++ks)
                bb[ks] = *(const bfrag*)&Wb[ks*32 + q8];
            f32x4 c0 = {0.f,0.f,0.f,0.f}, c1 = {0.f,0.f,0.f,0.f};
            __builtin_amdgcn_s_setprio(1);
            #pragma unroll
            for (int ks = 0; ks < 4; ++ks) {
                c0 = __builtin_amdgcn_mfma_f32_16x16x32_bf16(a[0][ks], bb[ks], c0, 0,0,0);
                c1 = __builtin_amdgcn_mfma_f32_16x16x32_bf16(a[1][ks], bb[ks], c1, 0,0,0);
            }
            __builtin_amdgcn_s_setprio(0);
            #pragma unroll
            for (int tm = 0; tm < 2; ++tm) {
                const f32x4 cc = tm ? c1 : c0;
                const int mrow0 = tm*16 + quad*4;     // 4 consecutive tokens
                const int pl = mrow0 >> 3;            // local patch
                const int p0 = mrow0 & 7;             // 0 or 4
                const int col = i0 + m16;
                const int cb  = nt & 7;               // column block = i>>4
                if (x == 0) {
                    short4 v;
                    v.x = f2bf(cc[0]); v.y = f2bf(cc[1]);
                    v.z = f2bf(cc[2]); v.w = f2bf(cc[3]);
                    *(short4*)&lds[QT + pl*1024 + col*8 + p0] = v;   // Qt[i][p]
                    #pragma unroll
                    for (int r = 0; r < 4; ++r)       // Qn[p][i], block-swz
                        lds[QN + pl*1024 + (p0 + r)*128
                            + ((cb ^ ((p0 + r) & 3)) << 4) + m16] = f2bf(cc[r]);
                } else if (x == 1) {
                    short4 v;
                    v.x = f2bf(cc[0]); v.y = f2bf(cc[1]);
                    v.z = f2bf(cc[2]); v.w = f2bf(cc[3]);
                    *(short4*)&lds[KT + pl*1024 + col*8 + p0] = v;   // Kt[j][p]
                    #pragma unroll
                    for (int r = 0; r < 4; ++r)       // Kn[p][j], block-swz
                        lds[KN + pl*1024 + (p0 + r)*128
                            + ((cb ^ ((p0 + r) & 3)) << 4) + m16] = f2bf(cc[r]);
                } else {
                    // Vs[p][j], column-group swizzled -> conflict-free
                    const int g = ((cb ^ (((pl & 1) << 1) | (p0 >> 2))) << 4);
                    #pragma unroll
                    for (int r = 0; r < 4; ++r)
                        lds[VS + pl*1024 + (p0 + r)*128 + g + m16] = f2bf(cc[r]);
                }
            }
        }
    }
    __syncthreads();   // barrier 1: the ONLY barrier (cross-wave QKV exchange)

    // ===== stats via Grams: sum(S)=sQ.sK, sum(S^2)=tr((QQ^T)(KK^T)) =====
    float rs2, nbias;
    {
        bfrag gq[4], gk[4], gs[4], ones;
        #pragma unroll
        for (int j = 0; j < 8; ++j) ones[j] = (short)0x3F80;   // bf16 1.0
        #pragma unroll
        for (int ks = 0; ks < 4; ++ks) {
            const int bswz = (((2*ks + (quad >> 1)) ^ (m16 & 3)) << 4) + (quad & 1)*8;
            gq[ks] = (m16 < 8) ? *(const bfrag*)&lds[QN + w*1024 + m16*128 + bswz] : bzero();
            gk[ks] = (m16 < 8) ? *(const bfrag*)&lds[KN + w*1024 + m16*128 + bswz] : bzero();
            gs[ks] = (m16 < 8) ? *(const bfrag*)&lds[QN + w*1024 + m16*128 + bswz]
                               : *(const bfrag*)&lds[KN + w*1024 + (m16 - 8)*128 + bswz];
        }
        f32x4 cg = {0.f,0.f,0.f,0.f}, ch = {0.f,0.f,0.f,0.f}, cs = {0.f,0.f,0.f,0.f};
        __builtin_amdgcn_s_setprio(1);
        #pragma unroll
        for (int ks = 0; ks < 4; ++ks) {
            cg = __builtin_amdgcn_mfma_f32_16x16x32_bf16(gq[ks], gq[ks], cg, 0,0,0);
            ch = __builtin_amdgcn_mfma_f32_16x16x32_bf16(gk[ks], gk[ks], ch, 0,0,0);
            cs = __builtin_amdgcn_mfma_f32_16x16x32_bf16(gs[ks], ones,  cs, 0,0,0);
        }
        __builtin_amdgcn_s_setprio(0);
        float gh = 0.f, sp = 0.f;
        #pragma unroll
        for (int r = 0; r < 4; ++r) {
            gh = fmaf(cg[r], ch[r], gh);
            sp = fmaf(cs[r], __shfl_xor(cs[r], 32), sp);     // sQ[p]*sK[p]
        }
        sp += __shfl_xor(sp, 16);
        #pragma unroll
        for (int off = 1; off <= 32; off <<= 1)
            gh += __shfl_xor(gh, off);
        const float mean = sp * (1.f / 16384.f);
        const float var  = gh * (1.f / 16384.f) - mean * mean;
        rs2   = rsqrtf(var + 1e-5f) * 1.44269504f;           // fold log2(e)
        nbias = -mean * rs2;
    }

    // ===== hoist Qt B-frags and V A-frags (own subregions die after) ======
    bfrag bs[8], av[4];
    #pragma unroll
    for (int nt = 0; nt < 8; ++nt)
        bs[nt] = (quad == 0) ? *(const bfrag*)&lds[QT + w*1024 + (nt*16 + m16)*8] : bzero();
    #pragma unroll
    for (int ks = 0; ks < 4; ++ks) {
        if (m16 < 8) {
            const int g = (((2*ks + (quad >> 1)) ^ (((w & 1) << 1) | (m16 >> 2))) << 4);
            av[ks] = *(const bfrag*)&lds[VS + w*1024 + m16*128 + g + (quad & 1)*8];
        } else if (m16 == 8) {                 // ones ROW -> C[8][i] = rowsum_i
            bfrag o;
            #pragma unroll
            for (int j = 0; j < 8; ++j) o[j] = (short)0x3F80;
            av[ks] = o;
        } else
            av[ks] = bzero();
    }
    // (no barrier 2: all LDS traffic below is wave-private; in-wave LDS RAW
    //  is ordered by the in-order DS queue)

    // ===== band loop: P chunks in OWN subregions of QT/QN/KN/VS ==========
    // P row = nt*16 + m16; chunk = nt>>1 -> {QT,QN,KN,VS}; in-chunk offset
    // (nt&1)*512 + m16*32 + swizzle. All compile-time after unroll.
    const int key2 = m16 >> 2;
    const int rowoff = m16 * 32;
    const int pw = w * 1024 + rowoff;
    f32x4 cc[8];
    #pragma unroll
    for (int nt = 0; nt < 8; ++nt) cc[nt] = (f32x4){0.f,0.f,0.f,0.f};

    #pragma unroll
    for (int ks = 0; ks < 4; ++ks) {
        #pragma unroll
        for (int jb = 0; jb < 2; ++jb) {
            const int band = ks*2 + jb;
            const bfrag amk = (quad == 0)
                ? *(const bfrag*)&lds[KT + w*1024 + (band*16 + m16)*8] : bzero();
            const int tw = (((jb*2 + (quad >> 1)) ^ key2) << 3) + (quad & 1)*4;
            #pragma unroll
            for (int nt = 0; nt < 8; ++nt) {
                const int zb = (nt >> 1) == 0 ? QT : (nt >> 1) == 1 ? QN
                             : (nt >> 1) == 2 ? KN : VS;
                f32x4 z = {0.f,0.f,0.f,0.f};
                __builtin_amdgcn_s_setprio(1);
                const f32x4 s4 = __builtin_amdgcn_mfma_f32_16x16x32_bf16(amk, bs[nt], z, 0,0,0);
                __builtin_amdgcn_s_setprio(0);
                short4 v;
                v.x = f2bf(__builtin_amdgcn_exp2f(fmaf(s4[0], rs2, nbias)));
                v.y = f2bf(__builtin_amdgcn_exp2f(fmaf(s4[1], rs2, nbias)));
                v.z = f2bf(__builtin_amdgcn_exp2f(fmaf(s4[2], rs2, nbias)));
                v.w = f2bf(__builtin_amdgcn_exp2f(fmaf(s4[3], rs2, nbias)));
                *(short4*)&lds[zb + pw + (nt & 1)*512 + tw] = v;
            }
        }
        __builtin_amdgcn_s_setprio(1);
        #pragma unroll
        for (int nt = 0; nt < 8; ++nt) {
            const int zb = (nt >> 1) == 0 ? QT : (nt >> 1) == 1 ? QN
                         : (nt >> 1) == 2 ? KN : VS;
            const bfrag bp = *(const bfrag*)
                &lds[zb + pw + (nt & 1)*512 + ((quad ^ key2) << 3)];
            cc[nt] = __builtin_amdgcn_mfma_f32_16x16x32_bf16(av[ks], bp, cc[nt], 0,0,0);
        }
        __builtin_amdgcn_s_setprio(0);
    }

    // ===== normalize once; ctx -> own KT subregion (after last amk read) ===
    #pragma unroll
    for (int nt = 0; nt < 8; ++nt) {
        const float s  = __shfl(cc[nt][0], 32 + m16);   // C[8][i] from quad-2
        const float is = 1.0f / s;
        if (quad < 2) {
            #pragma unroll
            for (int r = 0; r < 4; ++r) {
                const int p = quad*4 + r;
                lds[CTXK + w*1024 + p*128 + ((nt ^ (p & 3)) << 4) + m16] =
                    f2bf(cc[nt][r] * is);
            }
        }
    }

    // ===== fused out-GEMM (rotated pipeline, R13): prefetch wb[nt+1] ======
    bfrag ac[4];
    #pragma unroll
    for (int ks = 0; ks < 4; ++ks)
        ac[ks] = (m16 < 8)
            ? *(const bfrag*)&lds[CTXK + w*1024 + m16*128
                  + (((2*ks + (quad >> 1)) ^ (m16 & 3)) << 4) + (quad & 1)*8]
            : bzero();
    const short* Wo = Wout_pt + h * 16384;
    // output row permute: pat = pg*4+w -> (bb,dd,hh,ww); p = quad*4+r -> p1p2p3
    const int pat = pg*4 + w;
    const int bb2 = pat >> 5, rem = pat & 31;
    const int dd = rem >> 4, hh2 = (rem >> 2) & 3, ww2 = rem & 3;

    bfrag wbA[4], wbB[4];
    #pragma unroll
    for (int ks = 0; ks < 4; ++ks)
        wbA[ks] = *(const bfrag*)&Wo[m16*128 + ks*32 + q8];
    #pragma unroll 1
    for (int nt = 0; nt < 8; ++nt) {
        if (nt < 7) {
            #pragma unroll
            for (int ks = 0; ks < 4; ++ks)
                wbB[ks] = *(const bfrag*)&Wo[((nt+1)*16 + m16)*128 + ks*32 + q8];
        }
        f32x4 cc2 = {0.f,0.f,0.f,0.f};
        __builtin_amdgcn_s_setprio(1);
        #pragma unroll
        for (int ks = 0; ks < 4; ++ks)
            cc2 = __builtin_amdgcn_mfma_f32_16x16x32_bf16(ac[ks], wbA[ks], cc2, 0,0,0);
        __builtin_amdgcn_s_setprio(0);
        if (quad < 2) {
            #pragma unroll
            for (int r = 0; r < 4; ++r) {
                const int orow = bb2*256
                    + ((((dd*2 + quad)*4 + hh2)*2 + (r >> 1))*4 + ww2)*2 + (r & 1);
                atomicAdd(&out[(size_t)orow*128 + nt*16 + m16], cc2[r]);
            }
        }
        #pragma unroll
        for (int ks = 0; ks < 4; ++ks)
            wbA[ks] = wbB[ks];
    }
}

extern "C" void kernel_launch(void* const* d_in, const int* in_sizes, int n_in,
                              void* d_out, int out_size, void* d_ws, size_t ws_size,
                              hipStream_t stream) {
    const float* emb  = (const float*)d_in[0];   // (512, 8, 128)
    const float* Wq   = (const float*)d_in[1];   // (128, 1024)
    const float* Wk   = (const float*)d_in[2];
    const float* Wv   = (const float*)d_in[3];
    const float* Wout = (const float*)d_in[4];   // (1024, 128)
    float* out = (float*)d_out;                  // 524288 floats

    short* Wp      = (short*)d_ws;               // 768 KB
    short* Wout_pt = Wp + 393216;                // 256 KB

    convertW<<<128, 256, 0, stream>>>(Wq, Wk, Wv, Wout, Wp, Wout_pt, out);
    attn4<<<1024, 256, 0, stream>>>(emb, Wp, Wout_pt, out);
}

// Round 19
// 100.588 us; speedup vs baseline: 1.4431x; 1.0104x over previous
//
#include <hip/hip_runtime.h>
#include <hip/hip_bf16.h>
#include <math.h>

// Self_Attention_Local R24: R23 (=R16) + ONE delta: emb pre-converted to
//   bf16 in convertW. attn4's entry phase was fetching the same emb rows
//   8x (once per head) in fp32 AND converting with 64 f2bf/thread (~256
//   VALU of RTNE lowering) on the serial pre-barrier path. R24: convertW
//   converts emb once (524K elems, 16/thread, coalesced) into emb_bf in
//   workspace; attn4 loads bfrag directly (half the emb bytes, half the
//   load count, zero f2bf in the entry phase).
//   KEPT: all of R16 (transposed scores, atomic head-fusion, barrier-2-free
//   wave-private P chunks, rotated out-GEMM, XCD swizzle, setprio, f2bf
//   elsewhere, R8 keys, 6-shuffle butterfly).
//   DEAD: cvt_pk asm (R17), forced min-waves (R20/R21), i-splits (R19/R22),
//   cross-loop lookahead (R12). QUARANTINED: gh-shortcut (R10).

typedef short bfrag __attribute__((ext_vector_type(8)));   // 8 bf16 = 4 VGPRs
typedef float f32x4 __attribute__((ext_vector_type(4)));

static __device__ __forceinline__ short f2bf(float x) {
    __hip_bfloat16 h = __float2bfloat16(x);
    return __builtin_bit_cast(short, h);
}
static __device__ __forceinline__ bfrag bzero() {
    bfrag z;
    #pragma unroll
    for (int j = 0; j < 8; ++j) z[j] = 0;
    return z;
}

// ---------------- convertW: 128 blocks ----------------
__global__ __launch_bounds__(256) void convertW(
    const float* __restrict__ Wq, const float* __restrict__ Wk,
    const float* __restrict__ Wv, const float* __restrict__ Wout,
    const float* __restrict__ emb,
    short* __restrict__ Wp, short* __restrict__ Wout_pt,
    short* __restrict__ emb_bf,
    float* __restrict__ out)
{
    __shared__ short lt[128 * 33];          // union: [32][129] or [128][33]
    const int b = blockIdx.x, t = threadIdx.x;

    // zero out: 524288 floats = 131072 float4 = 128 blocks x 1024
    {
        float4* o4 = (float4*)out;
        const int zb = b * 1024 + t;
        #pragma unroll
        for (int k = 0; k < 4; ++k)
            o4[zb + k * 256] = make_float4(0.f, 0.f, 0.f, 0.f);
    }

    // emb fp32 -> bf16: 524288 elems = 131072 float4 = 128 blocks x 1024
    {
        const float4* e4 = (const float4*)emb;
        short4* b4 = (short4*)emb_bf;
        #pragma unroll
        for (int k = 0; k < 4; ++k) {
            const int idx = b * 1024 + k * 256 + t;
            const float4 x = e4[idx];
            short4 v;
            v.x = f2bf(x.x); v.y = f2bf(x.y);
            v.z = f2bf(x.z); v.w = f2bf(x.w);
            b4[idx] = v;
        }
    }

    if (b < 96) {
        const int x = b >> 5, h = (b >> 2) & 7, k0 = (b & 3) * 32;
        const float* W = (x == 0) ? Wq : (x == 1) ? Wk : Wv;
        #pragma unroll 4
        for (int rr = 0; rr < 16; ++rr) {
            const int k = rr * 2 + (t >> 7);          // 0..31
            const int i = t & 127;
            lt[k * 129 + i] = f2bf(W[(k0 + k) * 1024 + i * 8 + h]);
        }
        __syncthreads();
        short* dst = Wp + (x * 8 + h) * 16384;
        #pragma unroll
        for (int pp = 0; pp < 4; ++pp) {
            const int i  = pp * 32 + (t >> 3);
            const int kk = (t & 7) * 4;
            short4 v;
            v.x = lt[(kk + 0) * 129 + i]; v.y = lt[(kk + 1) * 129 + i];
            v.z = lt[(kk + 2) * 129 + i]; v.w = lt[(kk + 3) * 129 + i];
            *(short4*)&dst[i * 128 + k0 + kk] = v;
        }
    } else {
        const int b2 = b - 96, h = b2 >> 2, c0 = (b2 & 3) * 32;
        #pragma unroll 4
        for (int rr = 0; rr < 16; ++rr) {
            const int i = rr * 8 + (t >> 5);
            const int c = t & 31;
            lt[i * 33 + c] = f2bf(Wout[(i * 8 + h) * 128 + c0 + c]);
        }
        __syncthreads();
        short* dst = Wout_pt + h * 16384;
        #pragma unroll
        for (int pp = 0; pp < 4; ++pp) {
            const int c  = pp * 8 + (t >> 5);
            const int i0 = (t & 31) * 4;
            short4 v;
            v.x = lt[(i0 + 0) * 33 + c]; v.y = lt[(i0 + 1) * 33 + c];
            v.z = lt[(i0 + 2) * 33 + c]; v.w = lt[(i0 + 3) * 33 + c];
            *(short4*)&dst[(c0 + c) * 128 + i0] = v;
        }
    }
}

// ---------------- attn4 ----------------
// LDS zones (shorts), 40 KB:
//   QT [0..4095]      Qt[pl][i][p]    (own subregion dies -> P chunk 0)
//   KT [4096..8191]   Kt[pl][j][p]    (live through band loop; own CTX after)
//   QN [8192..12287]  Q natural, swz  (own subregion dies -> P chunk 1)
//   KN [12288..16383] K natural, swz  (own subregion dies -> P chunk 2)
//   VS [16384..20479] V natural, swz  (own subregion dies -> P chunk 3)
// P per wave: 4 chunks of 1024 shorts in the wave's OWN subregions.
#define QT   0
#define KT   4096
#define QN   8192
#define KN   12288
#define VS   16384
#define CTXK 4096

__global__ __launch_bounds__(256, 4) void attn4(
    const short* __restrict__ emb_bf,   // [4096][128] bf16 (pre-converted)
    const short* __restrict__ Wp,       // [3][8][128 i][128 k]
    const short* __restrict__ Wout_pt,  // [8][128 col][128 i]
    float* __restrict__ out)            // [4096][128] fp32, atomic target
{
    __shared__ short lds[20480];        // 40 KB
    const int bid = blockIdx.x;         // 0..1023
    // XCD-aware swizzle: heads of one patch-group share bid mod 8 -> same XCD
    const int pg  = bid & 127;          // patch group of 4
    const int h   = bid >> 7;           // head
    const int t   = threadIdx.x;
    const int w    = t >> 6;            // wave 0..3 (owns patch pl = w)
    const int lane = t & 63;
    const int m16  = lane & 15;
    const int quad = lane >> 4;
    const int q8   = quad * 8;

    // ================= QKV: (32x128) @ W_h (128x128) x3 =================
    {
        bfrag a[2][4];
        #pragma unroll
        for (int tm = 0; tm < 2; ++tm)
            #pragma unroll
            for (int ks = 0; ks < 4; ++ks)
                a[tm][ks] = *(const bfrag*)
                    &emb_bf[(size_t)(pg*32 + tm*16 + m16) * 128 + ks*32 + q8];

        #pragma unroll
        for (int tt = 0; tt < 6; ++tt) {
            const int nt = w * 6 + tt;            // 0..23 = {q,k,v} x 8 i-tiles
            const int x  = nt >> 3;
            const int i0 = (nt & 7) * 16;
            const short* Wb = Wp + ((x*8 + h)*128 + i0 + m16) * 128;
            bfrag bb[4];
            #pragma unroll
            for (int ks = 0; ks < 4; ++ks)
                bb[ks] = *(const bfrag*)&Wb[ks*32 + q8];
            f32x4 c0 = {0.f,0.f,0.f,0.f}, c1 = {0.f,0.f,0.f,0.f};
            __builtin_amdgcn_s_setprio(1);
            #pragma unroll
            for (int ks = 0; ks < 4; ++ks) {
                c0 = __builtin_amdgcn_mfma_f32_16x16x32_bf16(a[0][ks], bb[ks], c0, 0,0,0);
                c1 = __builtin_amdgcn_mfma_f32_16x16x32_bf16(a[1][ks], bb[ks], c1, 0,0,0);
            }
            __builtin_amdgcn_s_setprio(0);
            #pragma unroll
            for (int tm = 0; tm < 2; ++tm) {
                const f32x4 cc = tm ? c1 : c0;
                const int mrow0 = tm*16 + quad*4;     // 4 consecutive tokens
                const int pl = mrow0 >> 3;            // local patch
                const int p0 = mrow0 & 7;             // 0 or 4
                const int col = i0 + m16;
                const int cb  = nt & 7;               // column block = i>>4
                if (x == 0) {
                    short4 v;
                    v.x = f2bf(cc[0]); v.y = f2bf(cc[1]);
                    v.z = f2bf(cc[2]); v.w = f2bf(cc[3]);
                    *(short4*)&lds[QT + pl*1024 + col*8 + p0] = v;   // Qt[i][p]
                    #pragma unroll
                    for (int r = 0; r < 4; ++r)       // Qn[p][i], block-swz
                        lds[QN + pl*1024 + (p0 + r)*128
                            + ((cb ^ ((p0 + r) & 3)) << 4) + m16] = f2bf(cc[r]);
                } else if (x == 1) {
                    short4 v;
                    v.x = f2bf(cc[0]); v.y = f2bf(cc[1]);
                    v.z = f2bf(cc[2]); v.w = f2bf(cc[3]);
                    *(short4*)&lds[KT + pl*1024 + col*8 + p0] = v;   // Kt[j][p]
                    #pragma unroll
                    for (int r = 0; r < 4; ++r)       // Kn[p][j], block-swz
                        lds[KN + pl*1024 + (p0 + r)*128
                            + ((cb ^ ((p0 + r) & 3)) << 4) + m16] = f2bf(cc[r]);
                } else {
                    // Vs[p][j], column-group swizzled -> conflict-free
                    const int g = ((cb ^ (((pl & 1) << 1) | (p0 >> 2))) << 4);
                    #pragma unroll
                    for (int r = 0; r < 4; ++r)
                        lds[VS + pl*1024 + (p0 + r)*128 + g + m16] = f2bf(cc[r]);
                }
            }
        }
    }
    __syncthreads();   // barrier 1: the ONLY barrier (cross-wave QKV exchange)

    // ===== stats via Grams: sum(S)=sQ.sK, sum(S^2)=tr((QQ^T)(KK^T)) =====
    float rs2, nbias;
    {
        bfrag gq[4], gk[4], gs[4], ones;
        #pragma unroll
        for (int j = 0; j < 8; ++j) ones[j] = (short)0x3F80;   // bf16 1.0
        #pragma unroll
        for (int ks = 0; ks < 4; ++ks) {
            const int bswz = (((2*ks + (quad >> 1)) ^ (m16 & 3)) << 4) + (quad & 1)*8;
            gq[ks] = (m16 < 8) ? *(const bfrag*)&lds[QN + w*1024 + m16*128 + bswz] : bzero();
            gk[ks] = (m16 < 8) ? *(const bfrag*)&lds[KN + w*1024 + m16*128 + bswz] : bzero();
            gs[ks] = (m16 < 8) ? *(const bfrag*)&lds[QN + w*1024 + m16*128 + bswz]
                               : *(const bfrag*)&lds[KN + w*1024 + (m16 - 8)*128 + bswz];
        }
        f32x4 cg = {0.f,0.f,0.f,0.f}, ch = {0.f,0.f,0.f,0.f}, cs = {0.f,0.f,0.f,0.f};
        __builtin_amdgcn_s_setprio(1);
        #pragma unroll
        for (int ks = 0; ks < 4; ++ks) {
            cg = __builtin_amdgcn_mfma_f32_16x16x32_bf16(gq[ks], gq[ks], cg, 0,0,0);
            ch = __builtin_amdgcn_mfma_f32_16x16x32_bf16(gk[ks], gk[ks], ch, 0,0,0);
            cs = __builtin_amdgcn_mfma_f32_16x16x32_bf16(gs[ks], ones,  cs, 0,0,0);
        }
        __builtin_amdgcn_s_setprio(0);
        float gh = 0.f, sp = 0.f;
        #pragma unroll
        for (int r = 0; r < 4; ++r) {
            gh = fmaf(cg[r], ch[r], gh);
            sp = fmaf(cs[r], __shfl_xor(cs[r], 32), sp);     // sQ[p]*sK[p]
        }
        sp += __shfl_xor(sp, 16);
        #pragma unroll
        for (int off = 1; off <= 32; off <<= 1)
            gh += __shfl_xor(gh, off);
        const float mean = sp * (1.f / 16384.f);
        const float var  = gh * (1.f / 16384.f) - mean * mean;
        rs2   = rsqrtf(var + 1e-5f) * 1.44269504f;           // fold log2(e)
        nbias = -mean * rs2;
    }

    // ===== hoist Qt B-frags and V A-frags (own subregions die after) ======
    bfrag bs[8], av[4];
    #pragma unroll
    for (int nt = 0; nt < 8; ++nt)
        bs[nt] = (quad == 0) ? *(const bfrag*)&lds[QT + w*1024 + (nt*16 + m16)*8] : bzero();
    #pragma unroll
    for (int ks = 0; ks < 4; ++ks) {
        if (m16 < 8) {
            const int g = (((2*ks + (quad >> 1)) ^ (((w & 1) << 1) | (m16 >> 2))) << 4);
            av[ks] = *(const bfrag*)&lds[VS + w*1024 + m16*128 + g + (quad & 1)*8];
        } else if (m16 == 8) {                 // ones ROW -> C[8][i] = rowsum_i
            bfrag o;
            #pragma unroll
            for (int j = 0; j < 8; ++j) o[j] = (short)0x3F80;
            av[ks] = o;
        } else
            av[ks] = bzero();
    }
    // (no barrier 2: all LDS traffic below is wave-private; in-wave LDS RAW
    //  is ordered by the in-order DS queue)

    // ===== band loop: P chunks in OWN subregions of QT/QN/KN/VS ==========
    // P row = nt*16 + m16; chunk = nt>>1 -> {QT,QN,KN,VS}; in-chunk offset
    // (nt&1)*512 + m16*32 + swizzle. All compile-time after unroll.
    const int key2 = m16 >> 2;
    const int rowoff = m16 * 32;
    const int pw = w * 1024 + rowoff;
    f32x4 cc[8];
    #pragma unroll
    for (int nt = 0; nt < 8; ++nt) cc[nt] = (f32x4){0.f,0.f,0.f,0.f};

    #pragma unroll
    for (int ks = 0; ks < 4; ++ks) {
        #pragma unroll
        for (int jb = 0; jb < 2; ++jb) {
            const int band = ks*2 + jb;
            const bfrag amk = (quad == 0)
                ? *(const bfrag*)&lds[KT + w*1024 + (band*16 + m16)*8] : bzero();
            const int tw = (((jb*2 + (quad >> 1)) ^ key2) << 3) + (quad & 1)*4;
            #pragma unroll
            for (int nt = 0; nt < 8; ++nt) {
                const int zb = (nt >> 1) == 0 ? QT : (nt >> 1) == 1 ? QN
                             : (nt >> 1) == 2 ? KN : VS;
                f32x4 z = {0.f,0.f,0.f,0.f};
                __builtin_amdgcn_s_setprio(1);
                const f32x4 s4 = __builtin_amdgcn_mfma_f32_16x16x32_bf16(amk, bs[nt], z, 0,0,0);
                __builtin_amdgcn_s_setprio(0);
                short4 v;
                v.x = f2bf(__builtin_amdgcn_exp2f(fmaf(s4[0], rs2, nbias)));
                v.y = f2bf(__builtin_amdgcn_exp2f(fmaf(s4[1], rs2, nbias)));
                v.z = f2bf(__builtin_amdgcn_exp2f(fmaf(s4[2], rs2, nbias)));
                v.w = f2bf(__builtin_amdgcn_exp2f(fmaf(s4[3], rs2, nbias)));
                *(short4*)&lds[zb + pw + (nt & 1)*512 + tw] = v;
            }
        }
        __builtin_amdgcn_s_setprio(1);
        #pragma unroll
        for (int nt = 0; nt < 8; ++nt) {
            const int zb = (nt >> 1) == 0 ? QT : (nt >> 1) == 1 ? QN
                         : (nt >> 1) == 2 ? KN : VS;
            const bfrag bp = *(const bfrag*)
                &lds[zb + pw + (nt & 1)*512 + ((quad ^ key2) << 3)];
            cc[nt] = __builtin_amdgcn_mfma_f32_16x16x32_bf16(av[ks], bp, cc[nt], 0,0,0);
        }
        __builtin_amdgcn_s_setprio(0);
    }

    // ===== normalize once; ctx -> own KT subregion (after last amk read) ===
    #pragma unroll
    for (int nt = 0; nt < 8; ++nt) {
        const float s  = __shfl(cc[nt][0], 32 + m16);   // C[8][i] from quad-2
        const float is = 1.0f / s;
        if (quad < 2) {
            #pragma unroll
            for (int r = 0; r < 4; ++r) {
                const int p = quad*4 + r;
                lds[CTXK + w*1024 + p*128 + ((nt ^ (p & 3)) << 4) + m16] =
                    f2bf(cc[nt][r] * is);
            }
        }
    }

    // ===== fused out-GEMM (rotated pipeline, R13): prefetch wb[nt+1] ======
    bfrag ac[4];
    #pragma unroll
    for (int ks = 0; ks < 4; ++ks)
        ac[ks] = (m16 < 8)
            ? *(const bfrag*)&lds[CTXK + w*1024 + m16*128
                  + (((2*ks + (quad >> 1)) ^ (m16 & 3)) << 4) + (quad & 1)*8]
            : bzero();
    const short* Wo = Wout_pt + h * 16384;
    // output row permute: pat = pg*4+w -> (bb,dd,hh,ww); p = quad*4+r -> p1p2p3
    const int pat = pg*4 + w;
    const int bb2 = pat >> 5, rem = pat & 31;
    const int dd = rem >> 4, hh2 = (rem >> 2) & 3, ww2 = rem & 3;

    bfrag wbA[4], wbB[4];
    #pragma unroll
    for (int ks = 0; ks < 4; ++ks)
        wbA[ks] = *(const bfrag*)&Wo[m16*128 + ks*32 + q8];
    #pragma unroll 1
    for (int nt = 0; nt < 8; ++nt) {
        if (nt < 7) {
            #pragma unroll
            for (int ks = 0; ks < 4; ++ks)
                wbB[ks] = *(const bfrag*)&Wo[((nt+1)*16 + m16)*128 + ks*32 + q8];
        }
        f32x4 cc2 = {0.f,0.f,0.f,0.f};
        __builtin_amdgcn_s_setprio(1);
        #pragma unroll
        for (int ks = 0; ks < 4; ++ks)
            cc2 = __builtin_amdgcn_mfma_f32_16x16x32_bf16(ac[ks], wbA[ks], cc2, 0,0,0);
        __builtin_amdgcn_s_setprio(0);
        if (quad < 2) {
            #pragma unroll
            for (int r = 0; r < 4; ++r) {
                const int orow = bb2*256
                    + ((((dd*2 + quad)*4 + hh2)*2 + (r >> 1))*4 + ww2)*2 + (r & 1);
                atomicAdd(&out[(size_t)orow*128 + nt*16 + m16], cc2[r]);
            }
        }
        #pragma unroll
        for (int ks = 0; ks < 4; ++ks)
            wbA[ks] = wbB[ks];
    }
}

extern "C" void kernel_launch(void* const* d_in, const int* in_sizes, int n_in,
                              void* d_out, int out_size, void* d_ws, size_t ws_size,
                              hipStream_t stream) {
    const float* emb  = (const float*)d_in[0];   // (512, 8, 128)
    const float* Wq   = (const float*)d_in[1];   // (128, 1024)
    const float* Wk   = (const float*)d_in[2];
    const float* Wv   = (const float*)d_in[3];
    const float* Wout = (const float*)d_in[4];   // (1024, 128)
    float* out = (float*)d_out;                  // 524288 floats

    short* Wp      = (short*)d_ws;               // 768 KB
    short* Wout_pt = Wp + 393216;                // 256 KB
    short* emb_bf  = Wp + 524288;                // 1 MB (at d_ws + 1 MB)

    convertW<<<128, 256, 0, stream>>>(Wq, Wk, Wv, Wout, emb, Wp, Wout_pt, emb_bf, out);
    attn4<<<1024, 256, 0, stream>>>(emb_bf, Wp, Wout_pt, out);
}

// Round 20
// 99.925 us; speedup vs baseline: 1.4526x; 1.0066x over previous
//
#include <hip/hip_runtime.h>
#include <hip/hip_bf16.h>
#include <math.h>

// Self_Attention_Local R25: R24 + ONE delta: hoist the out-GEMM's initial
//   wbA load (4x b128 from L2-resident Wout_pt) ABOVE the normalize phase.
//   wbA depends only on global Wo (not on CTX), so the load's ~300cy L2
//   latency hides under normalize's serial 8-shuffle chain -- the same
//   mechanism as R13's rotated epilogue (the session's one scheduling win).
//   KEPT: R24 emb pre-conversion, R16 structure (transposed scores, atomic
//   head-fusion, barrier-2-free wave-private P chunks, rotated out-GEMM,
//   XCD swizzle, setprio, R8 keys, 6-shuffle butterfly).
//   DEAD: cvt_pk asm (R17), forced min-waves (R20/R21), i-splits (R19/R22),
//   cross-loop lookahead (R12). QUARANTINED: gh-shortcut (R10).
//   Status if this nulls: terminal kernel. Latency-distributed plateau --
//   no pipe >30% busy, VALU-floor arithmetic ~11us vs 40us wall, 5 schedule
//   nulls + 2 decomposition failures + all work-removal levers mined.

typedef short bfrag __attribute__((ext_vector_type(8)));   // 8 bf16 = 4 VGPRs
typedef float f32x4 __attribute__((ext_vector_type(4)));

static __device__ __forceinline__ short f2bf(float x) {
    __hip_bfloat16 h = __float2bfloat16(x);
    return __builtin_bit_cast(short, h);
}
static __device__ __forceinline__ bfrag bzero() {
    bfrag z;
    #pragma unroll
    for (int j = 0; j < 8; ++j) z[j] = 0;
    return z;
}

// ---------------- convertW: 128 blocks ----------------
__global__ __launch_bounds__(256) void convertW(
    const float* __restrict__ Wq, const float* __restrict__ Wk,
    const float* __restrict__ Wv, const float* __restrict__ Wout,
    const float* __restrict__ emb,
    short* __restrict__ Wp, short* __restrict__ Wout_pt,
    short* __restrict__ emb_bf,
    float* __restrict__ out)
{
    __shared__ short lt[128 * 33];          // union: [32][129] or [128][33]
    const int b = blockIdx.x, t = threadIdx.x;

    // zero out: 524288 floats = 131072 float4 = 128 blocks x 1024
    {
        float4* o4 = (float4*)out;
        const int zb = b * 1024 + t;
        #pragma unroll
        for (int k = 0; k < 4; ++k)
            o4[zb + k * 256] = make_float4(0.f, 0.f, 0.f, 0.f);
    }

    // emb fp32 -> bf16: 524288 elems = 131072 float4 = 128 blocks x 1024
    {
        const float4* e4 = (const float4*)emb;
        short4* b4 = (short4*)emb_bf;
        #pragma unroll
        for (int k = 0; k < 4; ++k) {
            const int idx = b * 1024 + k * 256 + t;
            const float4 x = e4[idx];
            short4 v;
            v.x = f2bf(x.x); v.y = f2bf(x.y);
            v.z = f2bf(x.z); v.w = f2bf(x.w);
            b4[idx] = v;
        }
    }

    if (b < 96) {
        const int x = b >> 5, h = (b >> 2) & 7, k0 = (b & 3) * 32;
        const float* W = (x == 0) ? Wq : (x == 1) ? Wk : Wv;
        #pragma unroll 4
        for (int rr = 0; rr < 16; ++rr) {
            const int k = rr * 2 + (t >> 7);          // 0..31
            const int i = t & 127;
            lt[k * 129 + i] = f2bf(W[(k0 + k) * 1024 + i * 8 + h]);
        }
        __syncthreads();
        short* dst = Wp + (x * 8 + h) * 16384;
        #pragma unroll
        for (int pp = 0; pp < 4; ++pp) {
            const int i  = pp * 32 + (t >> 3);
            const int kk = (t & 7) * 4;
            short4 v;
            v.x = lt[(kk + 0) * 129 + i]; v.y = lt[(kk + 1) * 129 + i];
            v.z = lt[(kk + 2) * 129 + i]; v.w = lt[(kk + 3) * 129 + i];
            *(short4*)&dst[i * 128 + k0 + kk] = v;
        }
    } else {
        const int b2 = b - 96, h = b2 >> 2, c0 = (b2 & 3) * 32;
        #pragma unroll 4
        for (int rr = 0; rr < 16; ++rr) {
            const int i = rr * 8 + (t >> 5);
            const int c = t & 31;
            lt[i * 33 + c] = f2bf(Wout[(i * 8 + h) * 128 + c0 + c]);
        }
        __syncthreads();
        short* dst = Wout_pt + h * 16384;
        #pragma unroll
        for (int pp = 0; pp < 4; ++pp) {
            const int c  = pp * 8 + (t >> 5);
            const int i0 = (t & 31) * 4;
            short4 v;
            v.x = lt[(i0 + 0) * 33 + c]; v.y = lt[(i0 + 1) * 33 + c];
            v.z = lt[(i0 + 2) * 33 + c]; v.w = lt[(i0 + 3) * 33 + c];
            *(short4*)&dst[(c0 + c) * 128 + i0] = v;
        }
    }
}

// ---------------- attn4 ----------------
// LDS zones (shorts), 40 KB:
//   QT [0..4095]      Qt[pl][i][p]    (own subregion dies -> P chunk 0)
//   KT [4096..8191]   Kt[pl][j][p]    (live through band loop; own CTX after)
//   QN [8192..12287]  Q natural, swz  (own subregion dies -> P chunk 1)
//   KN [12288..16383] K natural, swz  (own subregion dies -> P chunk 2)
//   VS [16384..20479] V natural, swz  (own subregion dies -> P chunk 3)
// P per wave: 4 chunks of 1024 shorts in the wave's OWN subregions.
#define QT   0
#define KT   4096
#define QN   8192
#define KN   12288
#define VS   16384
#define CTXK 4096

__global__ __launch_bounds__(256, 4) void attn4(
    const short* __restrict__ emb_bf,   // [4096][128] bf16 (pre-converted)
    const short* __restrict__ Wp,       // [3][8][128 i][128 k]
    const short* __restrict__ Wout_pt,  // [8][128 col][128 i]
    float* __restrict__ out)            // [4096][128] fp32, atomic target
{
    __shared__ short lds[20480];        // 40 KB
    const int bid = blockIdx.x;         // 0..1023
    // XCD-aware swizzle: heads of one patch-group share bid mod 8 -> same XCD
    const int pg  = bid & 127;          // patch group of 4
    const int h   = bid >> 7;           // head
    const int t   = threadIdx.x;
    const int w    = t >> 6;            // wave 0..3 (owns patch pl = w)
    const int lane = t & 63;
    const int m16  = lane & 15;
    const int quad = lane >> 4;
    const int q8   = quad * 8;

    // ================= QKV: (32x128) @ W_h (128x128) x3 =================
    {
        bfrag a[2][4];
        #pragma unroll
        for (int tm = 0; tm < 2; ++tm)
            #pragma unroll
            for (int ks = 0; ks < 4; ++ks)
                a[tm][ks] = *(const bfrag*)
                    &emb_bf[(size_t)(pg*32 + tm*16 + m16) * 128 + ks*32 + q8];

        #pragma unroll
        for (int tt = 0; tt < 6; ++tt) {
            const int nt = w * 6 + tt;            // 0..23 = {q,k,v} x 8 i-tiles
            const int x  = nt >> 3;
            const int i0 = (nt & 7) * 16;
            const short* Wb = Wp + ((x*8 + h)*128 + i0 + m16) * 128;
            bfrag bb[4];
            #pragma unroll
            for (int ks = 0; ks < 4; ++ks)
                bb[ks] = *(const bfrag*)&Wb[ks*32 + q8];
            f32x4 c0 = {0.f,0.f,0.f,0.f}, c1 = {0.f,0.f,0.f,0.f};
            __builtin_amdgcn_s_setprio(1);
            #pragma unroll
            for (int ks = 0; ks < 4; ++ks) {
                c0 = __builtin_amdgcn_mfma_f32_16x16x32_bf16(a[0][ks], bb[ks], c0, 0,0,0);
                c1 = __builtin_amdgcn_mfma_f32_16x16x32_bf16(a[1][ks], bb[ks], c1, 0,0,0);
            }
            __builtin_amdgcn_s_setprio(0);
            #pragma unroll
            for (int tm = 0; tm < 2; ++tm) {
                const f32x4 cc = tm ? c1 : c0;
                const int mrow0 = tm*16 + quad*4;     // 4 consecutive tokens
                const int pl = mrow0 >> 3;            // local patch
                const int p0 = mrow0 & 7;             // 0 or 4
                const int col = i0 + m16;
                const int cb  = nt & 7;               // column block = i>>4
                if (x == 0) {
                    short4 v;
                    v.x = f2bf(cc[0]); v.y = f2bf(cc[1]);
                    v.z = f2bf(cc[2]); v.w = f2bf(cc[3]);
                    *(short4*)&lds[QT + pl*1024 + col*8 + p0] = v;   // Qt[i][p]
                    #pragma unroll
                    for (int r = 0; r < 4; ++r)       // Qn[p][i], block-swz
                        lds[QN + pl*1024 + (p0 + r)*128
                            + ((cb ^ ((p0 + r) & 3)) << 4) + m16] = f2bf(cc[r]);
                } else if (x == 1) {
                    short4 v;
                    v.x = f2bf(cc[0]); v.y = f2bf(cc[1]);
                    v.z = f2bf(cc[2]); v.w = f2bf(cc[3]);
                    *(short4*)&lds[KT + pl*1024 + col*8 + p0] = v;   // Kt[j][p]
                    #pragma unroll
                    for (int r = 0; r < 4; ++r)       // Kn[p][j], block-swz
                        lds[KN + pl*1024 + (p0 + r)*128
                            + ((cb ^ ((p0 + r) & 3)) << 4) + m16] = f2bf(cc[r]);
                } else {
                    // Vs[p][j], column-group swizzled -> conflict-free
                    const int g = ((cb ^ (((pl & 1) << 1) | (p0 >> 2))) << 4);
                    #pragma unroll
                    for (int r = 0; r < 4; ++r)
                        lds[VS + pl*1024 + (p0 + r)*128 + g + m16] = f2bf(cc[r]);
                }
            }
        }
    }
    __syncthreads();   // barrier 1: the ONLY barrier (cross-wave QKV exchange)

    // ===== stats via Grams: sum(S)=sQ.sK, sum(S^2)=tr((QQ^T)(KK^T)) =====
    float rs2, nbias;
    {
        bfrag gq[4], gk[4], gs[4], ones;
        #pragma unroll
        for (int j = 0; j < 8; ++j) ones[j] = (short)0x3F80;   // bf16 1.0
        #pragma unroll
        for (int ks = 0; ks < 4; ++ks) {
            const int bswz = (((2*ks + (quad >> 1)) ^ (m16 & 3)) << 4) + (quad & 1)*8;
            gq[ks] = (m16 < 8) ? *(const bfrag*)&lds[QN + w*1024 + m16*128 + bswz] : bzero();
            gk[ks] = (m16 < 8) ? *(const bfrag*)&lds[KN + w*1024 + m16*128 + bswz] : bzero();
            gs[ks] = (m16 < 8) ? *(const bfrag*)&lds[QN + w*1024 + m16*128 + bswz]
                               : *(const bfrag*)&lds[KN + w*1024 + (m16 - 8)*128 + bswz];
        }
        f32x4 cg = {0.f,0.f,0.f,0.f}, ch = {0.f,0.f,0.f,0.f}, cs = {0.f,0.f,0.f,0.f};
        __builtin_amdgcn_s_setprio(1);
        #pragma unroll
        for (int ks = 0; ks < 4; ++ks) {
            cg = __builtin_amdgcn_mfma_f32_16x16x32_bf16(gq[ks], gq[ks], cg, 0,0,0);
            ch = __builtin_amdgcn_mfma_f32_16x16x32_bf16(gk[ks], gk[ks], ch, 0,0,0);
            cs = __builtin_amdgcn_mfma_f32_16x16x32_bf16(gs[ks], ones,  cs, 0,0,0);
        }
        __builtin_amdgcn_s_setprio(0);
        float gh = 0.f, sp = 0.f;
        #pragma unroll
        for (int r = 0; r < 4; ++r) {
            gh = fmaf(cg[r], ch[r], gh);
            sp = fmaf(cs[r], __shfl_xor(cs[r], 32), sp);     // sQ[p]*sK[p]
        }
        sp += __shfl_xor(sp, 16);
        #pragma unroll
        for (int off = 1; off <= 32; off <<= 1)
            gh += __shfl_xor(gh, off);
        const float mean = sp * (1.f / 16384.f);
        const float var  = gh * (1.f / 16384.f) - mean * mean;
        rs2   = rsqrtf(var + 1e-5f) * 1.44269504f;           // fold log2(e)
        nbias = -mean * rs2;
    }

    // ===== hoist Qt B-frags and V A-frags (own subregions die after) ======
    bfrag bs[8], av[4];
    #pragma unroll
    for (int nt = 0; nt < 8; ++nt)
        bs[nt] = (quad == 0) ? *(const bfrag*)&lds[QT + w*1024 + (nt*16 + m16)*8] : bzero();
    #pragma unroll
    for (int ks = 0; ks < 4; ++ks) {
        if (m16 < 8) {
            const int g = (((2*ks + (quad >> 1)) ^ (((w & 1) << 1) | (m16 >> 2))) << 4);
            av[ks] = *(const bfrag*)&lds[VS + w*1024 + m16*128 + g + (quad & 1)*8];
        } else if (m16 == 8) {                 // ones ROW -> C[8][i] = rowsum_i
            bfrag o;
            #pragma unroll
            for (int j = 0; j < 8; ++j) o[j] = (short)0x3F80;
            av[ks] = o;
        } else
            av[ks] = bzero();
    }
    // (no barrier 2: all LDS traffic below is wave-private; in-wave LDS RAW
    //  is ordered by the in-order DS queue)

    // ===== band loop: P chunks in OWN subregions of QT/QN/KN/VS ==========
    // P row = nt*16 + m16; chunk = nt>>1 -> {QT,QN,KN,VS}; in-chunk offset
    // (nt&1)*512 + m16*32 + swizzle. All compile-time after unroll.
    const int key2 = m16 >> 2;
    const int rowoff = m16 * 32;
    const int pw = w * 1024 + rowoff;
    f32x4 cc[8];
    #pragma unroll
    for (int nt = 0; nt < 8; ++nt) cc[nt] = (f32x4){0.f,0.f,0.f,0.f};

    #pragma unroll
    for (int ks = 0; ks < 4; ++ks) {
        #pragma unroll
        for (int jb = 0; jb < 2; ++jb) {
            const int band = ks*2 + jb;
            const bfrag amk = (quad == 0)
                ? *(const bfrag*)&lds[KT + w*1024 + (band*16 + m16)*8] : bzero();
            const int tw = (((jb*2 + (quad >> 1)) ^ key2) << 3) + (quad & 1)*4;
            #pragma unroll
            for (int nt = 0; nt < 8; ++nt) {
                const int zb = (nt >> 1) == 0 ? QT : (nt >> 1) == 1 ? QN
                             : (nt >> 1) == 2 ? KN : VS;
                f32x4 z = {0.f,0.f,0.f,0.f};
                __builtin_amdgcn_s_setprio(1);
                const f32x4 s4 = __builtin_amdgcn_mfma_f32_16x16x32_bf16(amk, bs[nt], z, 0,0,0);
                __builtin_amdgcn_s_setprio(0);
                short4 v;
                v.x = f2bf(__builtin_amdgcn_exp2f(fmaf(s4[0], rs2, nbias)));
                v.y = f2bf(__builtin_amdgcn_exp2f(fmaf(s4[1], rs2, nbias)));
                v.z = f2bf(__builtin_amdgcn_exp2f(fmaf(s4[2], rs2, nbias)));
                v.w = f2bf(__builtin_amdgcn_exp2f(fmaf(s4[3], rs2, nbias)));
                *(short4*)&lds[zb + pw + (nt & 1)*512 + tw] = v;
            }
        }
        __builtin_amdgcn_s_setprio(1);
        #pragma unroll
        for (int nt = 0; nt < 8; ++nt) {
            const int zb = (nt >> 1) == 0 ? QT : (nt >> 1) == 1 ? QN
                         : (nt >> 1) == 2 ? KN : VS;
            const bfrag bp = *(const bfrag*)
                &lds[zb + pw + (nt & 1)*512 + ((quad ^ key2) << 3)];
            cc[nt] = __builtin_amdgcn_mfma_f32_16x16x32_bf16(av[ks], bp, cc[nt], 0,0,0);
        }
        __builtin_amdgcn_s_setprio(0);
    }

    // ===== prefetch out-GEMM's first W tile (independent of CTX; its L2
    // ===== latency hides under the normalize shuffle chain below) =========
    const short* Wo = Wout_pt + h * 16384;
    bfrag wbA[4], wbB[4];
    #pragma unroll
    for (int ks = 0; ks < 4; ++ks)
        wbA[ks] = *(const bfrag*)&Wo[m16*128 + ks*32 + q8];

    // ===== normalize once; ctx -> own KT subregion (after last amk read) ===
    #pragma unroll
    for (int nt = 0; nt < 8; ++nt) {
        const float s  = __shfl(cc[nt][0], 32 + m16);   // C[8][i] from quad-2
        const float is = 1.0f / s;
        if (quad < 2) {
            #pragma unroll
            for (int r = 0; r < 4; ++r) {
                const int p = quad*4 + r;
                lds[CTXK + w*1024 + p*128 + ((nt ^ (p & 3)) << 4) + m16] =
                    f2bf(cc[nt][r] * is);
            }
        }
    }

    // ===== fused out-GEMM (rotated pipeline, R13): prefetch wb[nt+1] ======
    bfrag ac[4];
    #pragma unroll
    for (int ks = 0; ks < 4; ++ks)
        ac[ks] = (m16 < 8)
            ? *(const bfrag*)&lds[CTXK + w*1024 + m16*128
                  + (((2*ks + (quad >> 1)) ^ (m16 & 3)) << 4) + (quad & 1)*8]
            : bzero();
    // output row permute: pat = pg*4+w -> (bb,dd,hh,ww); p = quad*4+r -> p1p2p3
    const int pat = pg*4 + w;
    const int bb2 = pat >> 5, rem = pat & 31;
    const int dd = rem >> 4, hh2 = (rem >> 2) & 3, ww2 = rem & 3;

    #pragma unroll 1
    for (int nt = 0; nt < 8; ++nt) {
        if (nt < 7) {
            #pragma unroll
            for (int ks = 0; ks < 4; ++ks)
                wbB[ks] = *(const bfrag*)&Wo[((nt+1)*16 + m16)*128 + ks*32 + q8];
        }
        f32x4 cc2 = {0.f,0.f,0.f,0.f};
        __builtin_amdgcn_s_setprio(1);
        #pragma unroll
        for (int ks = 0; ks < 4; ++ks)
            cc2 = __builtin_amdgcn_mfma_f32_16x16x32_bf16(ac[ks], wbA[ks], cc2, 0,0,0);
        __builtin_amdgcn_s_setprio(0);
        if (quad < 2) {
            #pragma unroll
            for (int r = 0; r < 4; ++r) {
                const int orow = bb2*256
                    + ((((dd*2 + quad)*4 + hh2)*2 + (r >> 1))*4 + ww2)*2 + (r & 1);
                atomicAdd(&out[(size_t)orow*128 + nt*16 + m16], cc2[r]);
            }
        }
        #pragma unroll
        for (int ks = 0; ks < 4; ++ks)
            wbA[ks] = wbB[ks];
    }
}

extern "C" void kernel_launch(void* const* d_in, const int* in_sizes, int n_in,
                              void* d_out, int out_size, void* d_ws, size_t ws_size,
                              hipStream_t stream) {
    const float* emb  = (const float*)d_in[0];   // (512, 8, 128)
    const float* Wq   = (const float*)d_in[1];   // (128, 1024)
    const float* Wk   = (const float*)d_in[2];
    const float* Wv   = (const float*)d_in[3];
    const float* Wout = (const float*)d_in[4];   // (1024, 128)
    float* out = (float*)d_out;                  // 524288 floats

    short* Wp      = (short*)d_ws;               // 768 KB
    short* Wout_pt = Wp + 393216;                // 256 KB
    short* emb_bf  = Wp + 524288;                // 1 MB (at d_ws + 1 MB)

    convertW<<<128, 256, 0, stream>>>(Wq, Wk, Wv, Wout, emb, Wp, Wout_pt, emb_bf, out);
    attn4<<<1024, 256, 0, stream>>>(emb_bf, Wp, Wout_pt, out);
}